// Round 5
// baseline (173.923 us; speedup 1.0000x reference)
//
#include <hip/hip_runtime.h>
#include <math.h>

#define NQ 12
#define NS 4096
#define TT 32
#define BB 256
#define HH 128
#define NT 1024

typedef float v2f __attribute__((ext_vector_type(2)));

// ---------- compile-time CNOT-layer permutations (exactly per reference _cnot) ----------
constexpr unsigned cnot_g(unsigned x, int w, int r){
    int pc = 11 - w;                    // control wire w -> bit 11-w
    int pt = 11 - ((w + r) % 12);       // target wire (w+r)%12
    return x ^ (((x >> pc) & 1u) << pt);
}
constexpr unsigned Fperm(unsigned i, int r){      // new[i] = old[Fperm(i,r)]
    unsigned x = i;
    for (int w = 11; w >= 0; --w) x = cnot_g(x, w, r);
    return x;
}
constexpr unsigned Finv(unsigned i, int r){
    unsigned x = i;
    for (int w = 0; w < 12; ++w) x = cnot_g(x, w, r);
    return x;
}
constexpr unsigned F0closed(unsigned i){          // Fperm(.,1) closed form
    return i ^ ((i >> 1) & 0x7FFu) ^ ((i & 1u) << 10) ^ ((i & 1u) << 11);
}
// GF(2)-linear -> basis equality implies equality everywhere (constexpr step-limit safe).
constexpr bool check_all(){
    for (int b = 0; b < NQ; ++b){
        const unsigned e = 1u << b;
        if (F0closed(e) != Fperm(e,1)) return false;
        if (Fperm(Finv(e,1),1) != e) return false;
        if (Fperm(Finv(e,2),2) != e) return false;
    }
    if (F0closed(0u) != 0u || Fperm(0u,1) != 0u || Finv(0u,2) != 0u) return false;
    if (F0closed(0x5A3u) != Fperm(0x5A3u,1)) return false;
    if (Fperm(Finv(0xABCu,2),2) != 0xABCu) return false;
    return true;
}
static_assert(check_all(), "CNOT permutation closed forms wrong");
constexpr unsigned maskM(int k){
    unsigned m = 0;
    for (int b = 0; b < NQ; ++b) m |= ((Finv(1u<<b, 2) >> (11 - k)) & 1u) << b;
    return m;
}
constexpr unsigned gM0 = maskM(0), gM1 = maskM(1), gM2 = maskM(2), gM3 = maskM(3);
constexpr int sgn10(unsigned M, int K){ return __builtin_popcount((unsigned)K & (M >> 10)) & 1; }

// ---------- packed-fp32 complex helpers (VOP3P) ----------
__device__ __forceinline__ v2f pk_cmul(v2f m, v2f a){
    v2f t;
    asm("v_pk_mul_f32 %0, %1, %2 op_sel:[0,0] op_sel_hi:[0,1]"
        : "=v"(t) : "v"(m), "v"(a));
    asm("v_pk_fma_f32 %0, %1, %2, %0 op_sel:[1,1,0] op_sel_hi:[1,0,1] neg_lo:[1,0,0]"
        : "+v"(t) : "v"(m), "v"(a));
    return t;
}
__device__ __forceinline__ v2f pk_cfma(v2f m, v2f a, v2f acc){
    asm("v_pk_fma_f32 %0, %1, %2, %0 op_sel:[0,0,0] op_sel_hi:[0,1,1]"
        : "+v"(acc) : "v"(m), "v"(a));
    asm("v_pk_fma_f32 %0, %1, %2, %0 op_sel:[1,1,0] op_sel_hi:[1,0,1] neg_lo:[1,0,0]"
        : "+v"(acc) : "v"(m), "v"(a));
    return acc;
}
template<int NL, int NH>
__device__ __forceinline__ void pk_accsgn(v2f &acc, v2f ppb){
    if constexpr (NL==0 && NH==0)
        asm("v_pk_add_f32 %0, %1, %0" : "+v"(acc) : "v"(ppb));
    else if constexpr (NL==1 && NH==0)
        asm("v_pk_add_f32 %0, %1, %0 neg_lo:[1,0]" : "+v"(acc) : "v"(ppb));
    else if constexpr (NL==0 && NH==1)
        asm("v_pk_add_f32 %0, %1, %0 neg_hi:[1,0]" : "+v"(acc) : "v"(ppb));
    else
        asm("v_pk_add_f32 %0, %1, %0 neg_lo:[1,0] neg_hi:[1,0]" : "+v"(acc) : "v"(ppb));
}
template<int K>
__device__ __forceinline__ void expk4(const v2f* amp, v2f &a01, v2f &a23){
    const float pp = fmaf(amp[K].x, amp[K].x, amp[K].y * amp[K].y);
    v2f ppb; ppb.x = pp; ppb.y = pp;
    pk_accsgn<sgn10(gM0,K), sgn10(gM1,K)>(a01, ppb);
    pk_accsgn<sgn10(gM2,K), sgn10(gM3,K)>(a23, ppb);
    if constexpr (K < 3) expk4<K+1>(amp, a01, a23);
}

__device__ __forceinline__ int swz(int u){ return u ^ ((u >> 4) & 0xF); }

// 2 layer-1 Rot gates on the 2 thread-local bits; local bit0 <-> wire w0, bit1 <-> wire w0-1
__device__ __forceinline__ void rot2(v2f* s, const v2f (*m1)[4], int w0){
    {
        const v2f M00=m1[w0][0], M01=m1[w0][1], M10=m1[w0][2], M11=m1[w0][3];
        #pragma unroll
        for (int k = 0; k < 4; k += 2){
            const v2f a = s[k], bq = s[k+1];
            s[k]   = pk_cfma(M01, bq, pk_cmul(M00, a));
            s[k+1] = pk_cfma(M11, bq, pk_cmul(M10, a));
        }
    }
    {
        const v2f M00=m1[w0-1][0], M01=m1[w0-1][1], M10=m1[w0-1][2], M11=m1[w0-1][3];
        #pragma unroll
        for (int k = 0; k < 2; ++k){
            const v2f a = s[k], bq = s[k+2];
            s[k]   = pk_cfma(M01, bq, pk_cmul(M00, a));
            s[k+2] = pk_cfma(M11, bq, pk_cmul(M10, a));
        }
    }
}

extern "C" __global__ void __launch_bounds__(NT)
qlstm_kernel(const float* __restrict__ x,  const float* __restrict__ h0,
             const float* __restrict__ c0, const float* __restrict__ qw,
             const float* __restrict__ Wf, const float* __restrict__ bfp,
             const float* __restrict__ Wi, const float* __restrict__ bip,
             const float* __restrict__ Wc, const float* __restrict__ bcp,
             const float* __restrict__ Wo, const float* __restrict__ bop,
             float* __restrict__ out)
{
    __shared__ v2f S0[NS], S1[NS];         // double-buffered state (swizzled)
    __shared__ v2f matp[2][NQ][4];         // Rot matrices: m00,m01,m10,m11 (re,im)
    __shared__ v2f vv[NQ][2];              // per-wire product-state vectors (this step)
    __shared__ float xs[TT*8];             // preloaded x for this batch element
    __shared__ float4 red4[16];            // per-wave partial expectations

    const int b   = blockIdx.x;
    const int tid = threadIdx.x;

    // ---- one-time init ----
    if (tid < 2*NQ){
        const int l = tid / NQ, w = tid % NQ;
        const float phi = qw[(l*NQ + w)*3 + 0];
        const float th  = qw[(l*NQ + w)*3 + 1];
        const float om  = qw[(l*NQ + w)*3 + 2];
        float cth, sth, cap, sap, cam, sam;
        sincosf(0.5f*th, &sth, &cth);
        sincosf(0.5f*(phi+om), &sap, &cap);
        sincosf(0.5f*(phi-om), &sam, &cam);
        v2f m00; m00.x =  cap*cth; m00.y = -sap*cth;
        v2f m01; m01.x = -cam*sth; m01.y = -sam*sth;
        v2f m10; m10.x =  cam*sth; m10.y = -sam*sth;
        v2f m11; m11.x =  cap*cth; m11.y =  sap*cth;
        matp[l][w][0] = m00; matp[l][w][1] = m01;
        matp[l][w][2] = m10; matp[l][w][3] = m11;
    }
    if (tid >= 512 && tid < 768) xs[tid - 512] = x[b*(TT*8) + (tid - 512)];

    float wf=0,bfv=0,wi=0,biv=0,wc=0,bcv=0,wo=0,bov=0,c_reg=0,h_reg=0;
    if (tid < HH){
        c_reg = c0[b*HH + tid];  h_reg = h0[b*HH + tid];
        wf=Wf[tid]; bfv=bfp[tid]; wi=Wi[tid]; biv=bip[tid];
        wc=Wc[tid]; bcv=bcp[tid]; wo=Wo[tid]; bov=bop[tid];
    }
    __syncthreads();

    // vv for t=0: x wires by threads 512..519, h wires by threads 0..3
    if (tid >= 512 && tid < 520){
        const int w = tid - 512;
        float sa, ca; sincosf(0.5f*xs[w], &sa, &ca);
        const v2f M00=matp[0][w][0], M01=matp[0][w][1], M10=matp[0][w][2], M11=matp[0][w][3];
        v2f t0v; t0v.x = M00.x*ca + M01.y*sa; t0v.y = M00.y*ca - M01.x*sa;
        v2f t1v; t1v.x = M10.x*ca + M11.y*sa; t1v.y = M10.y*ca - M11.x*sa;
        vv[w][0] = t0v; vv[w][1] = t1v;
    }
    if (tid < 4){
        const int w = 8 + tid;
        float sa, ca; sincosf(0.5f*h0[b*HH + tid], &sa, &ca);
        const v2f M00=matp[0][w][0], M01=matp[0][w][1], M10=matp[0][w][2], M11=matp[0][w][3];
        v2f t0v; t0v.x = M00.x*ca + M01.y*sa; t0v.y = M00.y*ca - M01.x*sa;
        v2f t1v; t1v.x = M10.x*ca + M11.y*sa; t1v.y = M10.y*ca - M11.x*sa;
        vv[w][0] = t0v; vv[w][1] = t1v;
    }
    __syncthreads();

    // ---- per-thread constants ----
    const float sg0 = (__builtin_parity(tid & (gM0 & 0x3FFu)) ? -1.f : 1.f);
    const float sg1 = (__builtin_parity(tid & (gM1 & 0x3FFu)) ? -1.f : 1.f);
    const float sg2 = (__builtin_parity(tid & (gM2 & 0x3FFu)) ? -1.f : 1.f);
    const float sg3 = (__builtin_parity(tid & (gM3 & 0x3FFu)) ? -1.f : 1.f);
    // round-layout swizzled bases (swz is XOR-linear, k-part XORed per access)
    const int wR0 = swz(tid << 2);
    const int wR1 = swz(((tid >> 2) << 4) | (tid & 3));
    const int wR2 = swz(((tid >> 4) << 6) | (tid & 15));
    const int wR3 = swz(((tid >> 6) << 8) | (tid & 63));
    const int wR4 = swz(((tid >> 8) << 10) | (tid & 255));
    const int wR5 = swz(tid);
    // product-state selectors after F0 (j = (tid<<2)|k): wire w in 2..9 -> t_{9-w}^t_{10-w}
    const int s2 = ((tid>>7) ^ (tid>>8)) & 1;
    const int s3 = ((tid>>6) ^ (tid>>7)) & 1;
    const int s4 = ((tid>>5) ^ (tid>>6)) & 1;
    const int s5 = ((tid>>4) ^ (tid>>5)) & 1;
    const int s6 = ((tid>>3) ^ (tid>>4)) & 1;
    const int s7 = ((tid>>2) ^ (tid>>3)) & 1;
    const int s8 = ((tid>>1) ^ (tid>>2)) & 1;
    const int s9 = ( tid     ^ (tid>>1)) & 1;
    const int t9  = (tid >> 9) & 1;
    const int t89 = ((tid>>8) ^ (tid>>9)) & 1;
    const int t0  = tid & 1;
    const v2f* vf = &vv[0][0];

    v2f amp[4];

    #pragma unroll 1
    for (int t = 0; t < TT; ++t){
        // ---- direct build of post-CNOT0 product state: amp[k] = prod[F0((tid<<2)|k)] ----
        const v2f e2 = vf[ 4+s2], e3 = vf[ 6+s3], e4 = vf[ 8+s4], e5 = vf[10+s5];
        const v2f e6 = vf[12+s6], e7 = vf[14+s7], e8 = vf[16+s8], e9 = vf[18+s9];
        const v2f Q8 = pk_cmul(pk_cmul(pk_cmul(e2,e3), pk_cmul(e4,e5)),
                               pk_cmul(pk_cmul(e6,e7), pk_cmul(e8,e9)));
        const v2f U0 = pk_cmul(vf[0+t9],     vf[2+t89]);
        const v2f U1 = pk_cmul(vf[0+(t9^1)], vf[2+(t89^1)]);
        const v2f QU0 = pk_cmul(Q8, U0), QU1 = pk_cmul(Q8, U1);
        const v2f v10a = vf[20+t0], v10b = vf[20+(t0^1)];
        const v2f v11a = vf[22],    v11b = vf[23];
        amp[0] = pk_cmul(QU0, pk_cmul(v10a, v11a));   // k0=0,k1=0: w10 sel t0,   w11 sel 0
        amp[1] = pk_cmul(QU1, pk_cmul(v10a, v11b));   // k0=1,k1=0: w10 sel t0,   w11 sel 1
        amp[2] = pk_cmul(QU0, pk_cmul(v10b, v11b));   // k0=0,k1=1: w10 sel t0^1, w11 sel 1
        amp[3] = pk_cmul(QU1, pk_cmul(v10b, v11a));   // k0=1,k1=1: w10 sel t0^1, w11 sel 0

        // ---- 12 layer-1 Rot gates in 6 locality rounds (1q gates commute across wires) ----
        rot2(amp, matp[1], 11);                          // wires 11,10 (j bits 0,1)
        #pragma unroll
        for (int k = 0; k < 4; ++k) S0[wR0 ^ k] = amp[k];
        __syncthreads();
        // next step's x-wire vv (off critical tail; vv reads all done before sync above)
        if (tid >= 512 && tid < 520){
            const int w  = tid - 512;
            const int tn = (t + 1 < TT) ? t + 1 : t;
            float sa, ca; sincosf(0.5f*xs[tn*8 + w], &sa, &ca);
            const v2f M00=matp[0][w][0], M01=matp[0][w][1], M10=matp[0][w][2], M11=matp[0][w][3];
            v2f t0v; t0v.x = M00.x*ca + M01.y*sa; t0v.y = M00.y*ca - M01.x*sa;
            v2f t1v; t1v.x = M10.x*ca + M11.y*sa; t1v.y = M10.y*ca - M11.x*sa;
            vv[w][0] = t0v; vv[w][1] = t1v;
        }
        #pragma unroll
        for (int k = 0; k < 4; ++k) amp[k] = S0[wR1 ^ (k<<2)];
        rot2(amp, matp[1], 9);                           // wires 9,8
        #pragma unroll
        for (int k = 0; k < 4; ++k) S1[wR1 ^ (k<<2)] = amp[k];
        __syncthreads();
        #pragma unroll
        for (int k = 0; k < 4; ++k) amp[k] = S1[wR2 ^ ((k<<4)^k)];
        rot2(amp, matp[1], 7);                           // wires 7,6
        #pragma unroll
        for (int k = 0; k < 4; ++k) S0[wR2 ^ ((k<<4)^k)] = amp[k];
        __syncthreads();
        #pragma unroll
        for (int k = 0; k < 4; ++k) amp[k] = S0[wR3 ^ ((k<<6)^(k<<2))];
        rot2(amp, matp[1], 5);                           // wires 5,4
        #pragma unroll
        for (int k = 0; k < 4; ++k) S1[wR3 ^ ((k<<6)^(k<<2))] = amp[k];
        __syncthreads();
        #pragma unroll
        for (int k = 0; k < 4; ++k) amp[k] = S1[wR4 ^ (k<<8)];
        rot2(amp, matp[1], 3);                           // wires 3,2
        #pragma unroll
        for (int k = 0; k < 4; ++k) S0[wR4 ^ (k<<8)] = amp[k];
        __syncthreads();
        #pragma unroll
        for (int k = 0; k < 4; ++k) amp[k] = S0[wR5 ^ (k<<10)];
        rot2(amp, matp[1], 1);                           // wires 1,0

        // ---- CNOT layer 1 folded into <Z_g>; j = (k<<10)|tid ----
        v2f a01; a01.x = 0.f; a01.y = 0.f;
        v2f a23; a23.x = 0.f; a23.y = 0.f;
        expk4<0>(amp, a01, a23);
        float p0 = a01.x * sg0, p1 = a01.y * sg1;
        float p2s = a23.x * sg2, p3 = a23.y * sg3;
        #pragma unroll
        for (int mm = 1; mm < 64; mm <<= 1){
            p0  += __shfl_xor(p0,  mm, 64);
            p1  += __shfl_xor(p1,  mm, 64);
            p2s += __shfl_xor(p2s, mm, 64);
            p3  += __shfl_xor(p3,  mm, 64);
        }
        if ((tid & 63) == 0) red4[tid >> 6] = make_float4(p0, p1, p2s, p3);
        __syncthreads();

        // ---- LSTM update (regs) + next step's h-wire vv ----
        if (tid < HH){
            float q0 = 0.f, q1 = 0.f, q2 = 0.f, q3 = 0.f;
            #pragma unroll
            for (int i = 0; i < 16; ++i){
                const float4 r = red4[i];
                q0 += r.x; q1 += r.y; q2 += r.z; q3 += r.w;
            }
            const float fg = 1.f/(1.f + expf(-(q0*wf + bfv)));
            const float ig = 1.f/(1.f + expf(-(q1*wi + biv)));
            const float cg = tanhf(q2*wc + bcv);
            const float og = 1.f/(1.f + expf(-(q3*wo + bov)));
            c_reg = fg*c_reg + ig*cg;
            h_reg = og * tanhf(c_reg);
            if (tid < 4){
                const int w = 8 + tid;
                float sa, ca; sincosf(0.5f*h_reg, &sa, &ca);
                const v2f M00=matp[0][w][0], M01=matp[0][w][1], M10=matp[0][w][2], M11=matp[0][w][3];
                v2f t0v; t0v.x = M00.x*ca + M01.y*sa; t0v.y = M00.y*ca - M01.x*sa;
                v2f t1v; t1v.x = M10.x*ca + M11.y*sa; t1v.y = M10.y*ca - M11.x*sa;
                vv[w][0] = t0v; vv[w][1] = t1v;
            }
        }
        __syncthreads();
    }

    if (tid < HH){
        out[b*HH + tid]          = h_reg;
        out[BB*HH + b*HH + tid]  = c_reg;
    }
}

extern "C" void kernel_launch(void* const* d_in, const int* in_sizes, int n_in,
                              void* d_out, int out_size, void* d_ws, size_t ws_size,
                              hipStream_t stream)
{
    (void)in_sizes; (void)n_in; (void)d_ws; (void)ws_size; (void)out_size;
    const float* x  = (const float*)d_in[0];
    const float* h0 = (const float*)d_in[1];
    const float* c0 = (const float*)d_in[2];
    const float* qw = (const float*)d_in[3];
    const float* Wf = (const float*)d_in[4];
    const float* bf = (const float*)d_in[5];
    const float* Wi = (const float*)d_in[6];
    const float* bi = (const float*)d_in[7];
    const float* Wc = (const float*)d_in[8];
    const float* bc = (const float*)d_in[9];
    const float* Wo = (const float*)d_in[10];
    const float* bo = (const float*)d_in[11];
    qlstm_kernel<<<BB, NT, 0, stream>>>(x, h0, c0, qw, Wf, bf, Wi, bi,
                                        Wc, bc, Wo, bo, (float*)d_out);
}

// Round 6
// 165.974 us; speedup vs baseline: 1.0479x; 1.0479x over previous
//
#include <hip/hip_runtime.h>
#include <math.h>

#define NQ 12
#define NS 4096
#define TT 32
#define BB 256
#define HH 128
#define NT 512

typedef float v2f __attribute__((ext_vector_type(2)));

// ---------- compile-time CNOT-layer permutations (exactly per reference _cnot) ----------
constexpr unsigned cnot_g(unsigned x, int w, int r){
    int pc = 11 - w;                    // control wire w -> bit 11-w
    int pt = 11 - ((w + r) % 12);       // target wire (w+r)%12
    return x ^ (((x >> pc) & 1u) << pt);
}
constexpr unsigned Fperm(unsigned i, int r){      // new[i] = old[Fperm(i,r)]
    unsigned x = i;
    for (int w = 11; w >= 0; --w) x = cnot_g(x, w, r);
    return x;
}
constexpr unsigned Finv(unsigned i, int r){
    unsigned x = i;
    for (int w = 0; w < 12; ++w) x = cnot_g(x, w, r);
    return x;
}
constexpr unsigned F0closed(unsigned i){          // Fperm(.,1) closed form
    return i ^ ((i >> 1) & 0x7FFu) ^ ((i & 1u) << 10) ^ ((i & 1u) << 11);
}
// GF(2)-linear -> basis equality implies equality everywhere (constexpr step-limit safe).
constexpr bool check_all(){
    for (int b = 0; b < NQ; ++b){
        const unsigned e = 1u << b;
        if (F0closed(e) != Fperm(e,1)) return false;
        if (Fperm(Finv(e,1),1) != e) return false;
        if (Fperm(Finv(e,2),2) != e) return false;
    }
    if (F0closed(0u) != 0u || Fperm(0u,1) != 0u || Finv(0u,2) != 0u) return false;
    if (F0closed(0x5A3u) != Fperm(0x5A3u,1)) return false;
    if (Fperm(Finv(0xABCu,2),2) != 0xABCu) return false;
    return true;
}
static_assert(check_all(), "CNOT permutation closed forms wrong");
constexpr unsigned maskM(int k){
    unsigned m = 0;
    for (int b = 0; b < NQ; ++b) m |= ((Finv(1u<<b, 2) >> (11 - k)) & 1u) << b;
    return m;
}
constexpr unsigned gM0 = maskM(0), gM1 = maskM(1), gM2 = maskM(2), gM3 = maskM(3);
constexpr int sgn9(unsigned M, int K){ return __builtin_popcount((unsigned)K & (M >> 9)) & 1; }

// ---------- packed-fp32 complex helpers (VOP3P) ----------
__device__ __forceinline__ v2f pk_cmul(v2f m, v2f a){
    v2f t;
    asm("v_pk_mul_f32 %0, %1, %2 op_sel:[0,0] op_sel_hi:[0,1]"
        : "=v"(t) : "v"(m), "v"(a));
    asm("v_pk_fma_f32 %0, %1, %2, %0 op_sel:[1,1,0] op_sel_hi:[1,0,1] neg_lo:[1,0,0]"
        : "+v"(t) : "v"(m), "v"(a));
    return t;
}
__device__ __forceinline__ v2f pk_cfma(v2f m, v2f a, v2f acc){
    asm("v_pk_fma_f32 %0, %1, %2, %0 op_sel:[0,0,0] op_sel_hi:[0,1,1]"
        : "+v"(acc) : "v"(m), "v"(a));
    asm("v_pk_fma_f32 %0, %1, %2, %0 op_sel:[1,1,0] op_sel_hi:[1,0,1] neg_lo:[1,0,0]"
        : "+v"(acc) : "v"(m), "v"(a));
    return acc;
}
template<int NL, int NH>
__device__ __forceinline__ void pk_accsgn(v2f &acc, v2f ppb){
    if constexpr (NL==0 && NH==0)
        asm("v_pk_add_f32 %0, %1, %0" : "+v"(acc) : "v"(ppb));
    else if constexpr (NL==1 && NH==0)
        asm("v_pk_add_f32 %0, %1, %0 neg_lo:[1,0]" : "+v"(acc) : "v"(ppb));
    else if constexpr (NL==0 && NH==1)
        asm("v_pk_add_f32 %0, %1, %0 neg_hi:[1,0]" : "+v"(acc) : "v"(ppb));
    else
        asm("v_pk_add_f32 %0, %1, %0 neg_lo:[1,0] neg_hi:[1,0]" : "+v"(acc) : "v"(ppb));
}
template<int K>
__device__ __forceinline__ void expk(const v2f* amp, v2f &a01, v2f &a23){
    const float pp = fmaf(amp[K].x, amp[K].x, amp[K].y * amp[K].y);
    v2f ppb; ppb.x = pp; ppb.y = pp;
    pk_accsgn<sgn9(gM0,K), sgn9(gM1,K)>(a01, ppb);
    pk_accsgn<sgn9(gM2,K), sgn9(gM3,K)>(a23, ppb);
    if constexpr (K < 7) expk<K+1>(amp, a01, a23);
}

__device__ __forceinline__ int swz(int u){ return u ^ ((u >> 4) & 0xF); }
__device__ __forceinline__ float fsig(float xv){ return __fdividef(1.f, 1.f + __expf(-xv)); }
__device__ __forceinline__ float ftanh(float xv){
    const float e = __expf(-2.f * xv);
    return __fdividef(1.f - e, 1.f + e);
}

// 3 layer-1 Rot gates on the 3 thread-local bits; local bit lb <-> wire wtop-lb
__device__ __forceinline__ void rot3(v2f* s, const v2f (*m1)[4], int wtop){
    #pragma unroll
    for (int lb = 0; lb < 3; ++lb){
        const v2f M00 = m1[wtop-lb][0], M01 = m1[wtop-lb][1];
        const v2f M10 = m1[wtop-lb][2], M11 = m1[wtop-lb][3];
        #pragma unroll
        for (int k = 0; k < 8; ++k){
            if (k & (1 << lb)) continue;
            const int k1 = k | (1 << lb);
            const v2f a = s[k], b = s[k1];
            s[k]  = pk_cfma(M01, b, pk_cmul(M00, a));
            s[k1] = pk_cfma(M11, b, pk_cmul(M10, a));
        }
    }
}

extern "C" __global__ void __launch_bounds__(NT)
qlstm_kernel(const float* __restrict__ x,  const float* __restrict__ h0,
             const float* __restrict__ c0, const float* __restrict__ qw,
             const float* __restrict__ Wf, const float* __restrict__ bfp,
             const float* __restrict__ Wi, const float* __restrict__ bip,
             const float* __restrict__ Wc, const float* __restrict__ bcp,
             const float* __restrict__ Wo, const float* __restrict__ bop,
             float* __restrict__ out)
{
    __shared__ v2f S[NS];                  // single state buffer (swizzled)
    __shared__ v2f matp[2][NQ][4];         // Rot matrices: m00,m01,m10,m11 (re,im)
    __shared__ v2f vvx[8][2];              // per-x-wire product-state vectors (this step)
    __shared__ float xs[TT*8];             // preloaded x for this batch element
    __shared__ float4 red4[8];             // per-wave partial expectations

    const int b   = blockIdx.x;
    const int tid = threadIdx.x;

    // ---- one-time init ----
    if (tid < 2*NQ){
        const int l = tid / NQ, w = tid % NQ;
        const float phi = qw[(l*NQ + w)*3 + 0];
        const float th  = qw[(l*NQ + w)*3 + 1];
        const float om  = qw[(l*NQ + w)*3 + 2];
        float cth, sth, cap, sap, cam, sam;
        sincosf(0.5f*th, &sth, &cth);
        sincosf(0.5f*(phi+om), &sap, &cap);
        sincosf(0.5f*(phi-om), &sam, &cam);
        v2f m00; m00.x =  cap*cth; m00.y = -sap*cth;
        v2f m01; m01.x = -cam*sth; m01.y = -sam*sth;
        v2f m10; m10.x =  cam*sth; m10.y = -sam*sth;
        v2f m11; m11.x =  cap*cth; m11.y =  sap*cth;
        matp[l][w][0] = m00; matp[l][w][1] = m01;
        matp[l][w][2] = m10; matp[l][w][3] = m11;
    }
    if (tid >= 256) xs[tid - 256] = x[b*(TT*8) + (tid - 256)];

    float wf=0,bfv=0,wi=0,biv=0,wc=0,bcv=0,wo=0,bov=0,c_reg=0,h_reg=0;
    if (tid < HH){
        c_reg = c0[b*HH + tid];  h_reg = h0[b*HH + tid];
        wf=Wf[tid]; bfv=bfp[tid]; wi=Wi[tid]; biv=bip[tid];
        wc=Wc[tid]; bcv=bcp[tid]; wo=Wo[tid]; bov=bop[tid];
    }
    // uniform gate params for h-wires 0..3 (scalarized by compiler)
    float WfS[4], bfS[4], WiS[4], biS[4], WcS[4], bcS[4], WoS[4], boS[4];
    #pragma unroll
    for (int j = 0; j < 4; ++j){
        WfS[j]=Wf[j]; bfS[j]=bfp[j]; WiS[j]=Wi[j]; biS[j]=bip[j];
        WcS[j]=Wc[j]; bcS[j]=bcp[j]; WoS[j]=Wo[j]; boS[j]=bop[j];
    }
    __syncthreads();

    // hoist layer-0 matrices for h-wires (8..11) into registers
    v2f M8[4][4];
    #pragma unroll
    for (int j = 0; j < 4; ++j)
        #pragma unroll
        for (int m = 0; m < 4; ++m) M8[j][m] = matp[0][8+j][m];

    // per-thread h-wire state: c cells 0..3 + vv vectors (registers, redundant per thread)
    float c4[4]; v2f hv[4][2];
    #pragma unroll
    for (int j = 0; j < 4; ++j){
        c4[j] = c0[b*HH + j];
        const float hj = h0[b*HH + j];
        float sa, ca; sincosf(0.5f*hj, &sa, &ca);
        v2f t0v; t0v.x = M8[j][0].x*ca + M8[j][1].y*sa; t0v.y = M8[j][0].y*ca - M8[j][1].x*sa;
        v2f t1v; t1v.x = M8[j][2].x*ca + M8[j][3].y*sa; t1v.y = M8[j][2].y*ca - M8[j][3].x*sa;
        hv[j][0] = t0v; hv[j][1] = t1v;
    }
    // t=0 x-wire vv by threads 64..71
    if (tid >= 64 && tid < 72){
        const int w = tid - 64;
        float sa, ca; sincosf(0.5f*xs[w], &sa, &ca);
        const v2f M00=matp[0][w][0], M01=matp[0][w][1], M10=matp[0][w][2], M11=matp[0][w][3];
        v2f t0v; t0v.x = M00.x*ca + M01.y*sa; t0v.y = M00.y*ca - M01.x*sa;
        v2f t1v; t1v.x = M10.x*ca + M11.y*sa; t1v.y = M10.y*ca - M11.x*sa;
        vvx[w][0] = t0v; vvx[w][1] = t1v;
    }
    __syncthreads();

    // ---- per-thread constants ----
    const float sg0 = (__builtin_parity(tid & (gM0 & 0x1FFu)) ? -1.f : 1.f);
    const float sg1 = (__builtin_parity(tid & (gM1 & 0x1FFu)) ? -1.f : 1.f);
    const float sg2 = (__builtin_parity(tid & (gM2 & 0x1FFu)) ? -1.f : 1.f);
    const float sg3 = (__builtin_parity(tid & (gM3 & 0x1FFu)) ? -1.f : 1.f);
    // transition base addresses (XOR-linear swizzle; per-k parts XORed per access)
    const int bW1 = swz(tid << 3);                          // config A layout
    const int bR1 = swz(((tid >> 3) << 6) | (tid & 7));     // config B layout
    const int bR2 = swz((tid & 63) | ((tid >> 6) << 9));    // config C layout
    const int bR3 = swz(tid);                               // config D layout (+ k<<9)
    // product-state selectors after F0 (j = (tid<<3)|k): wire w in 2..8 -> tid bit (8-w)^(9-w)
    const int s2 = ((tid>>6) ^ (tid>>7)) & 1;
    const int s3 = ((tid>>5) ^ (tid>>6)) & 1;
    const int s4 = ((tid>>4) ^ (tid>>5)) & 1;
    const int s5 = ((tid>>3) ^ (tid>>4)) & 1;
    const int s6 = ((tid>>2) ^ (tid>>3)) & 1;
    const int s7 = ((tid>>1) ^ (tid>>2)) & 1;
    const int s8 = ( tid     ^ (tid>>1)) & 1;
    const int t8  = (tid >> 8) & 1;
    const int t78 = ((tid>>7) ^ (tid>>8)) & 1;
    const int t0  = tid & 1;
    const v2f* vf = &vvx[0][0];

    v2f amp[8];

    #pragma unroll 1
    for (int t = 0; t < TT; ++t){
        // ---- direct build of post-CNOT0 product state: amp[k] = prod[F0((tid<<3)|k)] ----
        const v2f e2 = vf[ 4+s2], e3 = vf[ 6+s3], e4 = vf[ 8+s4];
        const v2f e5 = vf[10+s5], e6 = vf[12+s6], e7 = vf[14+s7];
        const v2f e8 = s8 ? hv[0][1] : hv[0][0];
        const v2f Q  = pk_cmul(pk_cmul(pk_cmul(e2,e3), pk_cmul(e4,e5)),
                               pk_cmul(pk_cmul(e6,e7), e8));
        const v2f v0a = vf[0], v0b = vf[1], v1a = vf[2], v1b = vf[3];
        const v2f ua0 = t8 ? v0b : v0a,  ua1 = t8 ? v0a : v0b;
        const v2f ub0 = t78 ? v1b : v1a, ub1 = t78 ? v1a : v1b;
        const v2f QU0 = pk_cmul(Q, pk_cmul(ua0, ub0));
        const v2f QU1 = pk_cmul(Q, pk_cmul(ua1, ub1));
        const v2f v9a = hv[1][0], v9b = hv[1][1];
        const v2f v9s0 = t0 ? v9b : v9a, v9s1 = t0 ? v9a : v9b;
        const v2f v10a = hv[2][0], v10b = hv[2][1], v11a = hv[3][0], v11b = hv[3][1];
        const v2f P2_0 = pk_cmul(v10a, v11a), P2_1 = pk_cmul(v10a, v11b);
        const v2f P2_2 = pk_cmul(v10b, v11a), P2_3 = pk_cmul(v10b, v11b);
        #pragma unroll
        for (int k = 0; k < 8; ++k){
            const int g = k ^ (k >> 1);
            const v2f base = (k & 1) ? QU1 : QU0;
            const v2f w9   = (g & 4) ? v9s1 : v9s0;
            const v2f p2   = (g&3)==0 ? P2_0 : (g&3)==1 ? P2_1 : (g&3)==2 ? P2_2 : P2_3;
            amp[k] = pk_cmul(pk_cmul(base, w9), p2);
        }

        // ---- 12 layer-1 Rot gates, 4 rounds; T1/T2 are wave-local (no barrier) ----
        rot3(amp, matp[1], 11);                  // wires 11,10,9 (j bits 0..2)
        #pragma unroll
        for (int k = 0; k < 8; ++k) S[bW1 ^ k] = amp[k];              // T1 write (cfg A)
        asm volatile("s_waitcnt lgkmcnt(0)" ::: "memory");
        #pragma unroll
        for (int k = 0; k < 8; ++k) amp[k] = S[bR1 ^ ((k<<3)^(k>>1))]; // T1 read (cfg B)
        rot3(amp, matp[1], 8);                   // wires 8,7,6 (j bits 3..5)
        #pragma unroll
        for (int k = 0; k < 8; ++k) S[bR1 ^ ((k<<3)^(k>>1))] = amp[k]; // T2 write (in place)
        asm volatile("s_waitcnt lgkmcnt(0)" ::: "memory");
        #pragma unroll
        for (int k = 0; k < 8; ++k) amp[k] = S[bR2 ^ ((k<<6)^((k<<2)&15))]; // T2 read (cfg C)
        rot3(amp, matp[1], 5);                   // wires 5,4,3 (j bits 6..8)
        #pragma unroll
        for (int k = 0; k < 8; ++k) S[bR2 ^ ((k<<6)^((k<<2)&15))] = amp[k]; // T3 write (own wave region)
        __syncthreads();                                               // barrier 1
        #pragma unroll
        for (int k = 0; k < 8; ++k) amp[k] = S[bR3 + (k<<9)];          // T3 read (cfg D, cross-wave)
        rot3(amp, matp[1], 2);                   // wires 2,1,0 (j bits 9..11)

        // ---- CNOT layer 1 folded into <Z_g>; j = (k<<9)|tid ----
        v2f a01; a01.x = 0.f; a01.y = 0.f;
        v2f a23; a23.x = 0.f; a23.y = 0.f;
        expk<0>(amp, a01, a23);
        float p0 = a01.x * sg0, p1 = a01.y * sg1;
        float p2s = a23.x * sg2, p3 = a23.y * sg3;
        #pragma unroll
        for (int mm = 1; mm < 64; mm <<= 1){
            p0  += __shfl_xor(p0,  mm, 64);
            p1  += __shfl_xor(p1,  mm, 64);
            p2s += __shfl_xor(p2s, mm, 64);
            p3  += __shfl_xor(p3,  mm, 64);
        }
        if ((tid & 63) == 0) red4[tid >> 6] = make_float4(p0, p1, p2s, p3);
        // next step's x-wire vv (ordered vs next read by barrier 2)
        if (tid >= 64 && tid < 72){
            const int w  = tid - 64;
            const int tn = (t + 1 < TT) ? t + 1 : t;
            float sa, ca; __sincosf(0.5f*xs[tn*8 + w], &sa, &ca);
            const v2f M00=matp[0][w][0], M01=matp[0][w][1], M10=matp[0][w][2], M11=matp[0][w][3];
            v2f t0v; t0v.x = M00.x*ca + M01.y*sa; t0v.y = M00.y*ca - M01.x*sa;
            v2f t1v; t1v.x = M10.x*ca + M11.y*sa; t1v.y = M10.y*ca - M11.x*sa;
            vvx[w][0] = t0v; vvx[w][1] = t1v;
        }
        __syncthreads();                                               // barrier 2

        // ---- tail: ALL threads compute q, h0..3, next hv in registers (no more barriers) ----
        float q0=0.f, q1=0.f, q2=0.f, q3=0.f;
        #pragma unroll
        for (int i = 0; i < 8; ++i){
            const float4 r = red4[i];
            q0 += r.x; q1 += r.y; q2 += r.z; q3 += r.w;
        }
        #pragma unroll
        for (int j = 0; j < 4; ++j){
            const float fg = fsig (q0*WfS[j] + bfS[j]);
            const float ig = fsig (q1*WiS[j] + biS[j]);
            const float cg = ftanh(q2*WcS[j] + bcS[j]);
            const float og = fsig (q3*WoS[j] + boS[j]);
            c4[j] = fg*c4[j] + ig*cg;
            const float hj = og * ftanh(c4[j]);
            float sa, ca; __sincosf(0.5f*hj, &sa, &ca);
            v2f t0v; t0v.x = M8[j][0].x*ca + M8[j][1].y*sa; t0v.y = M8[j][0].y*ca - M8[j][1].x*sa;
            v2f t1v; t1v.x = M8[j][2].x*ca + M8[j][3].y*sa; t1v.y = M8[j][2].y*ca - M8[j][3].x*sa;
            hv[j][0] = t0v; hv[j][1] = t1v;
        }
        // personal LSTM state for output (threads 0..127), overlaps with next step's front
        if (tid < HH){
            const float fg = fsig (q0*wf + bfv);
            const float ig = fsig (q1*wi + biv);
            const float cg = ftanh(q2*wc + bcv);
            const float og = fsig (q3*wo + bov);
            c_reg = fg*c_reg + ig*cg;
            h_reg = og * ftanh(c_reg);
        }
    }

    if (tid < HH){
        out[b*HH + tid]          = h_reg;
        out[BB*HH + b*HH + tid]  = c_reg;
    }
}

extern "C" void kernel_launch(void* const* d_in, const int* in_sizes, int n_in,
                              void* d_out, int out_size, void* d_ws, size_t ws_size,
                              hipStream_t stream)
{
    (void)in_sizes; (void)n_in; (void)d_ws; (void)ws_size; (void)out_size;
    const float* x  = (const float*)d_in[0];
    const float* h0 = (const float*)d_in[1];
    const float* c0 = (const float*)d_in[2];
    const float* qw = (const float*)d_in[3];
    const float* Wf = (const float*)d_in[4];
    const float* bf = (const float*)d_in[5];
    const float* Wi = (const float*)d_in[6];
    const float* bi = (const float*)d_in[7];
    const float* Wc = (const float*)d_in[8];
    const float* bc = (const float*)d_in[9];
    const float* Wo = (const float*)d_in[10];
    const float* bo = (const float*)d_in[11];
    qlstm_kernel<<<BB, NT, 0, stream>>>(x, h0, c0, qw, Wf, bf, Wi, bi,
                                        Wc, bc, Wo, bo, (float*)d_out);
}

// Round 7
// 128.917 us; speedup vs baseline: 1.3491x; 1.2875x over previous
//
#include <hip/hip_runtime.h>
#include <math.h>

#define NQ 12
#define NS 4096
#define TT 32
#define BB 256
#define HH 128
#define NT 512

typedef float v2f __attribute__((ext_vector_type(2)));

// ---------- compile-time CNOT-layer permutations (exactly per reference _cnot) ----------
constexpr unsigned cnot_g(unsigned x, int w, int r){
    int pc = 11 - w;                    // control wire w -> bit 11-w
    int pt = 11 - ((w + r) % 12);       // target wire (w+r)%12
    return x ^ (((x >> pc) & 1u) << pt);
}
constexpr unsigned Fperm(unsigned i, int r){      // new[i] = old[Fperm(i,r)]
    unsigned x = i;
    for (int w = 11; w >= 0; --w) x = cnot_g(x, w, r);
    return x;
}
constexpr unsigned Finv(unsigned i, int r){
    unsigned x = i;
    for (int w = 0; w < 12; ++w) x = cnot_g(x, w, r);
    return x;
}
constexpr unsigned F0closed(unsigned i){          // Fperm(.,1) closed form
    return i ^ ((i >> 1) & 0x7FFu) ^ ((i & 1u) << 10) ^ ((i & 1u) << 11);
}
// GF(2)-linear -> basis equality implies equality everywhere (constexpr step-limit safe).
constexpr bool check_all(){
    for (int b = 0; b < NQ; ++b){
        const unsigned e = 1u << b;
        if (F0closed(e) != Fperm(e,1)) return false;
        if (Fperm(Finv(e,1),1) != e) return false;
        if (Fperm(Finv(e,2),2) != e) return false;
    }
    if (F0closed(0u) != 0u || Fperm(0u,1) != 0u || Finv(0u,2) != 0u) return false;
    if (F0closed(0x5A3u) != Fperm(0x5A3u,1)) return false;
    if (Fperm(Finv(0xABCu,2),2) != 0xABCu) return false;
    return true;
}
static_assert(check_all(), "CNOT permutation closed forms wrong");
constexpr unsigned maskM(int k){
    unsigned m = 0;
    for (int b = 0; b < NQ; ++b) m |= ((Finv(1u<<b, 2) >> (11 - k)) & 1u) << b;
    return m;
}
constexpr unsigned gM0 = maskM(0), gM1 = maskM(1), gM2 = maskM(2), gM3 = maskM(3);
constexpr int sgn9(unsigned M, int K){ return __builtin_popcount((unsigned)K & (M >> 9)) & 1; }

// ---------- packed-fp32 complex helpers (VOP3P) ----------
__device__ __forceinline__ v2f pk_cmul(v2f m, v2f a){
    v2f t;
    asm("v_pk_mul_f32 %0, %1, %2 op_sel:[0,0] op_sel_hi:[0,1]"
        : "=v"(t) : "v"(m), "v"(a));
    asm("v_pk_fma_f32 %0, %1, %2, %0 op_sel:[1,1,0] op_sel_hi:[1,0,1] neg_lo:[1,0,0]"
        : "+v"(t) : "v"(m), "v"(a));
    return t;
}
__device__ __forceinline__ v2f pk_cfma(v2f m, v2f a, v2f acc){
    asm("v_pk_fma_f32 %0, %1, %2, %0 op_sel:[0,0,0] op_sel_hi:[0,1,1]"
        : "+v"(acc) : "v"(m), "v"(a));
    asm("v_pk_fma_f32 %0, %1, %2, %0 op_sel:[1,1,0] op_sel_hi:[1,0,1] neg_lo:[1,0,0]"
        : "+v"(acc) : "v"(m), "v"(a));
    return acc;
}
template<int NL, int NH>
__device__ __forceinline__ void pk_accsgn(v2f &acc, v2f ppb){
    if constexpr (NL==0 && NH==0)
        asm("v_pk_add_f32 %0, %1, %0" : "+v"(acc) : "v"(ppb));
    else if constexpr (NL==1 && NH==0)
        asm("v_pk_add_f32 %0, %1, %0 neg_lo:[1,0]" : "+v"(acc) : "v"(ppb));
    else if constexpr (NL==0 && NH==1)
        asm("v_pk_add_f32 %0, %1, %0 neg_hi:[1,0]" : "+v"(acc) : "v"(ppb));
    else
        asm("v_pk_add_f32 %0, %1, %0 neg_lo:[1,0] neg_hi:[1,0]" : "+v"(acc) : "v"(ppb));
}
template<int K>
__device__ __forceinline__ void expk(const v2f* amp, v2f &a01, v2f &a23){
    const float pp = fmaf(amp[K].x, amp[K].x, amp[K].y * amp[K].y);
    v2f ppb; ppb.x = pp; ppb.y = pp;
    pk_accsgn<sgn9(gM0,K), sgn9(gM1,K)>(a01, ppb);
    pk_accsgn<sgn9(gM2,K), sgn9(gM3,K)>(a23, ppb);
    if constexpr (K < 7) expk<K+1>(amp, a01, a23);
}

// ---------- DPP wave-64 sum: result lands in lane 63 (VALU-only, no DS) ----------
template<int C>
__device__ __forceinline__ float dppadd(float v){
    return v + __int_as_float(
        __builtin_amdgcn_update_dpp(0, __float_as_int(v), C, 0xF, 0xF, true));
}
__device__ __forceinline__ float wsum(float v){
    v = dppadd<0x111>(v);   // row_shr:1
    v = dppadd<0x112>(v);   // row_shr:2
    v = dppadd<0x114>(v);   // row_shr:4
    v = dppadd<0x118>(v);   // row_shr:8  -> lane15 of each row16 = row sum
    v = dppadd<0x142>(v);   // row_bcast:15 -> lane31 = rows0+1, lane63 = rows2+3
    v = dppadd<0x143>(v);   // row_bcast:31 -> lane63 = total
    return v;
}

// ---------- rank-5 bank swizzle: slot(j) = j ^ ((j>>3)&0x1F) ----------
// bank bits (slot 0..4): b0=j0^j3 b1=j1^j4 b2=j2^j5 b3=j3^j6 b4=j4^j7.
// Rank 5 on each per-instruction varying set:
//   A-write vary{j3..j8}; B vary{j0..2,j6..8}; C/D vary{j0..j5}  -> all 2-way (free).
// Worked checks: tid=5,k=3: slot=46; tid=5,m=3 (cfgB): 5^27=30 = slot(29);
//   tid=357,m=5 (cfgC): 2593^328=2921 = slot(2917); (cfgD): 361+5*512=2921. OK.

__device__ __forceinline__ float fsig(float xv){ return 1.f/(1.f + expf(-xv)); }

// 3 layer-1 Rot gates on the 3 thread-local bits; local bit lb <-> wire wtop-lb
__device__ __forceinline__ void rot3(v2f* s, const v2f (*m1)[4], int wtop){
    #pragma unroll
    for (int lb = 0; lb < 3; ++lb){
        const v2f M00 = m1[wtop-lb][0], M01 = m1[wtop-lb][1];
        const v2f M10 = m1[wtop-lb][2], M11 = m1[wtop-lb][3];
        #pragma unroll
        for (int k = 0; k < 8; ++k){
            if (k & (1 << lb)) continue;
            const int k1 = k | (1 << lb);
            const v2f a = s[k], b = s[k1];
            s[k]  = pk_cfma(M01, b, pk_cmul(M00, a));
            s[k1] = pk_cfma(M11, b, pk_cmul(M10, a));
        }
    }
}

extern "C" __global__ void __launch_bounds__(NT)
qlstm_kernel(const float* __restrict__ x,  const float* __restrict__ h0,
             const float* __restrict__ c0, const float* __restrict__ qw,
             const float* __restrict__ Wf, const float* __restrict__ bfp,
             const float* __restrict__ Wi, const float* __restrict__ bip,
             const float* __restrict__ Wc, const float* __restrict__ bcp,
             const float* __restrict__ Wo, const float* __restrict__ bop,
             float* __restrict__ out)
{
    __shared__ v2f S[NS];                  // single state buffer (rank-5 swizzled)
    __shared__ v2f matp[2][NQ][4];         // Rot matrices: m00,m01,m10,m11 (re,im)
    __shared__ v2f vv[NQ][2];              // per-wire product-state vectors (this step)
    __shared__ float xs[TT*8];             // preloaded x for this batch element
    __shared__ float4 red4[8];             // per-wave partial expectations

    const int b   = blockIdx.x;
    const int tid = threadIdx.x;

    // ---- one-time init ----
    if (tid < 2*NQ){
        const int l = tid / NQ, w = tid % NQ;
        const float phi = qw[(l*NQ + w)*3 + 0];
        const float th  = qw[(l*NQ + w)*3 + 1];
        const float om  = qw[(l*NQ + w)*3 + 2];
        float cth, sth, cap, sap, cam, sam;
        sincosf(0.5f*th, &sth, &cth);
        sincosf(0.5f*(phi+om), &sap, &cap);
        sincosf(0.5f*(phi-om), &sam, &cam);
        v2f m00; m00.x =  cap*cth; m00.y = -sap*cth;
        v2f m01; m01.x = -cam*sth; m01.y = -sam*sth;
        v2f m10; m10.x =  cam*sth; m10.y = -sam*sth;
        v2f m11; m11.x =  cap*cth; m11.y =  sap*cth;
        matp[l][w][0] = m00; matp[l][w][1] = m01;
        matp[l][w][2] = m10; matp[l][w][3] = m11;
    }
    if (tid >= 256) xs[tid - 256] = x[b*(TT*8) + (tid - 256)];

    float wf=0,bfv=0,wi=0,biv=0,wc=0,bcv=0,wo=0,bov=0,c_reg=0,h_reg=0;
    if (tid < HH){
        c_reg = c0[b*HH + tid];  h_reg = h0[b*HH + tid];
        wf=Wf[tid]; bfv=bfp[tid]; wi=Wi[tid]; biv=bip[tid];
        wc=Wc[tid]; bcv=bcp[tid]; wo=Wo[tid]; bov=bop[tid];
    }
    __syncthreads();

    // vv for t=0: x wires by threads 128..135, h wires by threads 0..3
    if (tid >= 128 && tid < 136){
        const int w = tid - 128;
        float sa, ca; sincosf(0.5f*xs[w], &sa, &ca);
        const v2f M00=matp[0][w][0], M01=matp[0][w][1], M10=matp[0][w][2], M11=matp[0][w][3];
        v2f t0v; t0v.x = M00.x*ca + M01.y*sa; t0v.y = M00.y*ca - M01.x*sa;
        v2f t1v; t1v.x = M10.x*ca + M11.y*sa; t1v.y = M10.y*ca - M11.x*sa;
        vv[w][0] = t0v; vv[w][1] = t1v;
    }
    if (tid < 4){
        const int w = 8 + tid;
        float sa, ca; sincosf(0.5f*h0[b*HH + tid], &sa, &ca);
        const v2f M00=matp[0][w][0], M01=matp[0][w][1], M10=matp[0][w][2], M11=matp[0][w][3];
        v2f t0v; t0v.x = M00.x*ca + M01.y*sa; t0v.y = M00.y*ca - M01.x*sa;
        v2f t1v; t1v.x = M10.x*ca + M11.y*sa; t1v.y = M10.y*ca - M11.x*sa;
        vv[w][0] = t0v; vv[w][1] = t1v;
    }
    __syncthreads();

    // ---- per-thread constants ----
    const float sg0 = (__builtin_parity(tid & (gM0 & 0x1FFu)) ? -1.f : 1.f);
    const float sg1 = (__builtin_parity(tid & (gM1 & 0x1FFu)) ? -1.f : 1.f);
    const float sg2 = (__builtin_parity(tid & (gM2 & 0x1FFu)) ? -1.f : 1.f);
    const float sg3 = (__builtin_parity(tid & (gM3 & 0x1FFu)) ? -1.f : 1.f);
    // per-config swizzled bases; per-k masks are compile-time XOR constants
    const int bA = (tid << 3) ^ (tid & 31);                                  // cfg A: ^ k
    const int bB = (tid & 7) ^ (((tid >> 3) & 3) << 3) ^ ((tid >> 3) << 6);  // cfg B: ^ 9m
    const int bC = ((tid & 63) ^ ((tid >> 3) & 7)) | ((tid >> 6) << 9);      // cfg C: ^ (m<<6 | (m&3)<<3)
    const int bD = tid ^ ((tid >> 3) & 31);                                  // cfg D: + (m<<9)
    // product-state selectors after F0 (j = (tid<<3)|k): wire w in 2..8 -> tid bit (8-w)^(9-w)
    const int s2 = ((tid>>6) ^ (tid>>7)) & 1;
    const int s3 = ((tid>>5) ^ (tid>>6)) & 1;
    const int s4 = ((tid>>4) ^ (tid>>5)) & 1;
    const int s5 = ((tid>>3) ^ (tid>>4)) & 1;
    const int s6 = ((tid>>2) ^ (tid>>3)) & 1;
    const int s7 = ((tid>>1) ^ (tid>>2)) & 1;
    const int s8 = ( tid     ^ (tid>>1)) & 1;
    const int t8  = (tid >> 8) & 1;
    const int t78 = ((tid>>7) ^ (tid>>8)) & 1;
    const int t0  = tid & 1;
    const v2f* vf = &vv[0][0];

    v2f amp[8];

    #pragma unroll 1
    for (int t = 0; t < TT; ++t){
        // ---- direct build of post-CNOT0 product state: amp[k] = prod[F0((tid<<3)|k)] ----
        const v2f e2 = vf[ 4+s2], e3 = vf[ 6+s3], e4 = vf[ 8+s4];
        const v2f e5 = vf[10+s5], e6 = vf[12+s6], e7 = vf[14+s7], e8 = vf[16+s8];
        const v2f Q  = pk_cmul(pk_cmul(pk_cmul(e2,e3), pk_cmul(e4,e5)),
                               pk_cmul(pk_cmul(e6,e7), e8));
        const v2f v0a = vf[0], v0b = vf[1], v1a = vf[2], v1b = vf[3];
        const v2f ua0 = t8 ? v0b : v0a,  ua1 = t8 ? v0a : v0b;
        const v2f ub0 = t78 ? v1b : v1a, ub1 = t78 ? v1a : v1b;
        const v2f QU0 = pk_cmul(Q, pk_cmul(ua0, ub0));
        const v2f QU1 = pk_cmul(Q, pk_cmul(ua1, ub1));
        const v2f v9a = vf[18], v9b = vf[19];
        const v2f v9s0 = t0 ? v9b : v9a, v9s1 = t0 ? v9a : v9b;
        const v2f v10a = vf[20], v10b = vf[21], v11a = vf[22], v11b = vf[23];
        const v2f P2_0 = pk_cmul(v10a, v11a), P2_1 = pk_cmul(v10a, v11b);
        const v2f P2_2 = pk_cmul(v10b, v11a), P2_3 = pk_cmul(v10b, v11b);
        #pragma unroll
        for (int k = 0; k < 8; ++k){
            const int g = k ^ (k >> 1);
            const v2f base = (k & 1) ? QU1 : QU0;
            const v2f w9   = (g & 4) ? v9s1 : v9s0;
            const v2f p2   = (g&3)==0 ? P2_0 : (g&3)==1 ? P2_1 : (g&3)==2 ? P2_2 : P2_3;
            amp[k] = pk_cmul(pk_cmul(base, w9), p2);
        }

        // ---- 12 layer-1 Rot gates in 4 rounds; conflict-free rank-5 swizzle ----
        rot3(amp, matp[1], 11);                  // wires 11,10,9 (j bits 0..2)
        #pragma unroll
        for (int k = 0; k < 8; ++k) S[bA ^ k] = amp[k];                 // T1 write (cfg A)
        __syncthreads();
        #pragma unroll
        for (int k = 0; k < 8; ++k) amp[k] = S[bB ^ (9*k)];             // T1 read (cfg B)
        rot3(amp, matp[1], 8);                   // wires 8,7,6 (j bits 3..5)
        #pragma unroll
        for (int k = 0; k < 8; ++k) S[bB ^ (9*k)] = amp[k];             // T2 write (in place)
        __syncthreads();
        #pragma unroll
        for (int k = 0; k < 8; ++k) amp[k] = S[bC ^ ((k<<6) | ((k&3)<<3))]; // T2 read (cfg C)
        rot3(amp, matp[1], 5);                   // wires 5,4,3 (j bits 6..8)
        #pragma unroll
        for (int k = 0; k < 8; ++k) S[bC ^ ((k<<6) | ((k&3)<<3))] = amp[k]; // T3 write (in place)
        __syncthreads();
        #pragma unroll
        for (int k = 0; k < 8; ++k) amp[k] = S[bD + (k<<9)];            // T3 read (cfg D)
        rot3(amp, matp[1], 2);                   // wires 2,1,0 (j bits 9..11)

        // ---- CNOT layer 1 folded into <Z_g>; j = (k<<9)|tid ----
        v2f a01; a01.x = 0.f; a01.y = 0.f;
        v2f a23; a23.x = 0.f; a23.y = 0.f;
        expk<0>(amp, a01, a23);
        float p0 = a01.x * sg0, p1 = a01.y * sg1;
        float p2s = a23.x * sg2, p3 = a23.y * sg3;
        p0 = wsum(p0); p1 = wsum(p1); p2s = wsum(p2s); p3 = wsum(p3);   // lane 63 has sums
        if ((tid & 63) == 63) red4[tid >> 6] = make_float4(p0, p1, p2s, p3);
        // next step's x-wire vv (safe: all vv reads this step done before T1 barrier)
        if (tid >= 128 && tid < 136){
            const int w  = tid - 128;
            const int tn = (t + 1 < TT) ? t + 1 : t;
            float sa, ca; sincosf(0.5f*xs[tn*8 + w], &sa, &ca);
            const v2f M00=matp[0][w][0], M01=matp[0][w][1], M10=matp[0][w][2], M11=matp[0][w][3];
            v2f t0v; t0v.x = M00.x*ca + M01.y*sa; t0v.y = M00.y*ca - M01.x*sa;
            v2f t1v; t1v.x = M10.x*ca + M11.y*sa; t1v.y = M10.y*ca - M11.x*sa;
            vv[w][0] = t0v; vv[w][1] = t1v;
        }
        __syncthreads();

        // ---- LSTM update (regs) + next step's h-wire vv ----
        if (tid < HH){
            const float4 r0=red4[0], r1=red4[1], r2=red4[2], r3=red4[3];
            const float4 r4=red4[4], r5=red4[5], r6=red4[6], r7=red4[7];
            const float q0 = ((r0.x+r1.x)+(r2.x+r3.x)) + ((r4.x+r5.x)+(r6.x+r7.x));
            const float q1 = ((r0.y+r1.y)+(r2.y+r3.y)) + ((r4.y+r5.y)+(r6.y+r7.y));
            const float q2 = ((r0.z+r1.z)+(r2.z+r3.z)) + ((r4.z+r5.z)+(r6.z+r7.z));
            const float q3 = ((r0.w+r1.w)+(r2.w+r3.w)) + ((r4.w+r5.w)+(r6.w+r7.w));
            const float fg = fsig(q0*wf + bfv);
            const float ig = fsig(q1*wi + biv);
            const float cg = tanhf(q2*wc + bcv);
            const float og = fsig(q3*wo + bov);
            c_reg = fg*c_reg + ig*cg;
            h_reg = og * tanhf(c_reg);
            if (tid < 4){
                const int w = 8 + tid;
                float sa, ca; sincosf(0.5f*h_reg, &sa, &ca);
                const v2f M00=matp[0][w][0], M01=matp[0][w][1], M10=matp[0][w][2], M11=matp[0][w][3];
                v2f t0v; t0v.x = M00.x*ca + M01.y*sa; t0v.y = M00.y*ca - M01.x*sa;
                v2f t1v; t1v.x = M10.x*ca + M11.y*sa; t1v.y = M10.y*ca - M11.x*sa;
                vv[w][0] = t0v; vv[w][1] = t1v;
            }
        }
        __syncthreads();
    }

    if (tid < HH){
        out[b*HH + tid]          = h_reg;
        out[BB*HH + b*HH + tid]  = c_reg;
    }
}

extern "C" void kernel_launch(void* const* d_in, const int* in_sizes, int n_in,
                              void* d_out, int out_size, void* d_ws, size_t ws_size,
                              hipStream_t stream)
{
    (void)in_sizes; (void)n_in; (void)d_ws; (void)ws_size; (void)out_size;
    const float* x  = (const float*)d_in[0];
    const float* h0 = (const float*)d_in[1];
    const float* c0 = (const float*)d_in[2];
    const float* qw = (const float*)d_in[3];
    const float* Wf = (const float*)d_in[4];
    const float* bf = (const float*)d_in[5];
    const float* Wi = (const float*)d_in[6];
    const float* bi = (const float*)d_in[7];
    const float* Wc = (const float*)d_in[8];
    const float* bc = (const float*)d_in[9];
    const float* Wo = (const float*)d_in[10];
    const float* bo = (const float*)d_in[11];
    qlstm_kernel<<<BB, NT, 0, stream>>>(x, h0, c0, qw, Wf, bf, Wi, bi,
                                        Wc, bc, Wo, bo, (float*)d_out);
}

// Round 8
// 119.598 us; speedup vs baseline: 1.4542x; 1.0779x over previous
//
#include <hip/hip_runtime.h>
#include <math.h>

#define NQ 12
#define NS 4096
#define TT 32
#define BB 256
#define HH 128
#define NT 512

typedef float v2f __attribute__((ext_vector_type(2)));
typedef float v4f __attribute__((ext_vector_type(4)));

// ---------- compile-time CNOT-layer permutations (exactly per reference _cnot) ----------
constexpr unsigned cnot_g(unsigned x, int w, int r){
    int pc = 11 - w;                    // control wire w -> bit 11-w
    int pt = 11 - ((w + r) % 12);       // target wire (w+r)%12
    return x ^ (((x >> pc) & 1u) << pt);
}
constexpr unsigned Fperm(unsigned i, int r){      // new[i] = old[Fperm(i,r)]
    unsigned x = i;
    for (int w = 11; w >= 0; --w) x = cnot_g(x, w, r);
    return x;
}
constexpr unsigned Finv(unsigned i, int r){
    unsigned x = i;
    for (int w = 0; w < 12; ++w) x = cnot_g(x, w, r);
    return x;
}
constexpr unsigned F0closed(unsigned i){          // Fperm(.,1) closed form
    return i ^ ((i >> 1) & 0x7FFu) ^ ((i & 1u) << 10) ^ ((i & 1u) << 11);
}
// GF(2)-linear -> basis equality implies equality everywhere (constexpr step-limit safe).
constexpr bool check_all(){
    for (int b = 0; b < NQ; ++b){
        const unsigned e = 1u << b;
        if (F0closed(e) != Fperm(e,1)) return false;
        if (Fperm(Finv(e,1),1) != e) return false;
        if (Fperm(Finv(e,2),2) != e) return false;
    }
    if (F0closed(0u) != 0u || Fperm(0u,1) != 0u || Finv(0u,2) != 0u) return false;
    if (F0closed(0x5A3u) != Fperm(0x5A3u,1)) return false;
    if (Fperm(Finv(0xABCu,2),2) != 0xABCu) return false;
    return true;
}
static_assert(check_all(), "CNOT permutation closed forms wrong");
constexpr unsigned maskM(int k){
    unsigned m = 0;
    for (int b = 0; b < NQ; ++b) m |= ((Finv(1u<<b, 2) >> (11 - k)) & 1u) << b;
    return m;
}
constexpr unsigned gM0 = maskM(0), gM1 = maskM(1), gM2 = maskM(2), gM3 = maskM(3);
constexpr int sgn9(unsigned M, int K){ return __builtin_popcount((unsigned)K & (M >> 9)) & 1; }

// ---------- packed-fp32 complex helpers (VOP3P) ----------
__device__ __forceinline__ v2f pk_cmul(v2f m, v2f a){
    v2f t;
    asm("v_pk_mul_f32 %0, %1, %2 op_sel:[0,0] op_sel_hi:[0,1]"
        : "=v"(t) : "v"(m), "v"(a));
    asm("v_pk_fma_f32 %0, %1, %2, %0 op_sel:[1,1,0] op_sel_hi:[1,0,1] neg_lo:[1,0,0]"
        : "+v"(t) : "v"(m), "v"(a));
    return t;
}
__device__ __forceinline__ v2f pk_cfma(v2f m, v2f a, v2f acc){
    asm("v_pk_fma_f32 %0, %1, %2, %0 op_sel:[0,0,0] op_sel_hi:[0,1,1]"
        : "+v"(acc) : "v"(m), "v"(a));
    asm("v_pk_fma_f32 %0, %1, %2, %0 op_sel:[1,1,0] op_sel_hi:[1,0,1] neg_lo:[1,0,0]"
        : "+v"(acc) : "v"(m), "v"(a));
    return acc;
}
template<int NL, int NH>
__device__ __forceinline__ void pk_accsgn(v2f &acc, v2f ppb){
    if constexpr (NL==0 && NH==0)
        asm("v_pk_add_f32 %0, %1, %0" : "+v"(acc) : "v"(ppb));
    else if constexpr (NL==1 && NH==0)
        asm("v_pk_add_f32 %0, %1, %0 neg_lo:[1,0]" : "+v"(acc) : "v"(ppb));
    else if constexpr (NL==0 && NH==1)
        asm("v_pk_add_f32 %0, %1, %0 neg_hi:[1,0]" : "+v"(acc) : "v"(ppb));
    else
        asm("v_pk_add_f32 %0, %1, %0 neg_lo:[1,0] neg_hi:[1,0]" : "+v"(acc) : "v"(ppb));
}
template<int K>
__device__ __forceinline__ void expk(const v2f* amp, v2f &a01, v2f &a23){
    const float pp = fmaf(amp[K].x, amp[K].x, amp[K].y * amp[K].y);
    v2f ppb; ppb.x = pp; ppb.y = pp;
    pk_accsgn<sgn9(gM0,K), sgn9(gM1,K)>(a01, ppb);
    pk_accsgn<sgn9(gM2,K), sgn9(gM3,K)>(a23, ppb);
    if constexpr (K < 7) expk<K+1>(amp, a01, a23);
}

// ---------- DPP wave-64 sum: result lands in lane 63 (VALU-only, no DS) ----------
template<int C>
__device__ __forceinline__ float dppadd(float v){
    return v + __int_as_float(
        __builtin_amdgcn_update_dpp(0, __float_as_int(v), C, 0xF, 0xF, true));
}
__device__ __forceinline__ float wsum(float v){
    v = dppadd<0x111>(v);   // row_shr:1
    v = dppadd<0x112>(v);   // row_shr:2
    v = dppadd<0x114>(v);   // row_shr:4
    v = dppadd<0x118>(v);   // row_shr:8  -> lane15 of each row16 = row sum
    v = dppadd<0x142>(v);   // row_bcast:15 -> lane31 = rows0+1, lane63 = rows2+3
    v = dppadd<0x143>(v);   // row_bcast:31 -> lane63 = total
    return v;
}

// ---------- rank-5 bank swizzle: slot(j) = j ^ ((j>>3)&0x1F) ----------
// All four per-instruction lane->bank maps have GF(2)-rank 5 -> every b64 access
// is the minimum 2-way (free). Swizzle touches only bits 0..4, so slot bits 9..11
// = j bits 9..11 = wave bits: each wave's 512-slot region is preserved.
// T1 (A->B) and T2 (B->C) keep wave bits identical on both sides => WAVE-LOCAL:
// same-wave DS ops execute in order, so a compiler fence suffices (no barrier).
// T3 (C->D) crosses waves => __syncthreads. read-D(t) vs write-A(t+1) is ordered
// by the red4 barrier (read-D before it, write-A after it).

__device__ __forceinline__ float fsig(float xv){ return __fdividef(1.f, 1.f + __expf(-xv)); }
__device__ __forceinline__ float ftanh(float xv){
    const float e = __expf(-2.f * xv);
    return __fdividef(1.f - e, 1.f + e);
}

// 3 layer-1 Rot gates on the 3 thread-local bits; local bit lb <-> wire wtop-lb
__device__ __forceinline__ void rot3(v2f* s, const v2f (*m1)[4], int wtop){
    #pragma unroll
    for (int lb = 0; lb < 3; ++lb){
        const v2f M00 = m1[wtop-lb][0], M01 = m1[wtop-lb][1];
        const v2f M10 = m1[wtop-lb][2], M11 = m1[wtop-lb][3];
        #pragma unroll
        for (int k = 0; k < 8; ++k){
            if (k & (1 << lb)) continue;
            const int k1 = k | (1 << lb);
            const v2f a = s[k], b = s[k1];
            s[k]  = pk_cfma(M01, b, pk_cmul(M00, a));
            s[k1] = pk_cfma(M11, b, pk_cmul(M10, a));
        }
    }
}

extern "C" __global__ void __launch_bounds__(NT)
qlstm_kernel(const float* __restrict__ x,  const float* __restrict__ h0,
             const float* __restrict__ c0, const float* __restrict__ qw,
             const float* __restrict__ Wf, const float* __restrict__ bfp,
             const float* __restrict__ Wi, const float* __restrict__ bip,
             const float* __restrict__ Wc, const float* __restrict__ bcp,
             const float* __restrict__ Wo, const float* __restrict__ bop,
             float* __restrict__ out)
{
    __shared__ v2f S[NS];                  // single state buffer (rank-5 swizzled)
    __shared__ v2f matp[2][NQ][4];         // Rot matrices: m00,m01,m10,m11 (re,im)
    __shared__ v2f vvx[8][2];              // x-wire product-state vectors (this step)
    __shared__ v4f vvh[8][4];              // per-WAVE h-wire vectors (wave-private!)
    __shared__ float xs[TT*8];             // preloaded x for this batch element
    __shared__ float4 red4[8];             // per-wave partial expectations

    const int b    = blockIdx.x;
    const int tid  = threadIdx.x;
    const int wave = tid >> 6;
    const int lane = tid & 63;

    // ---- one-time init ----
    if (tid < 2*NQ){
        const int l = tid / NQ, w = tid % NQ;
        const float phi = qw[(l*NQ + w)*3 + 0];
        const float th  = qw[(l*NQ + w)*3 + 1];
        const float om  = qw[(l*NQ + w)*3 + 2];
        float cth, sth, cap, sap, cam, sam;
        sincosf(0.5f*th, &sth, &cth);
        sincosf(0.5f*(phi+om), &sap, &cap);
        sincosf(0.5f*(phi-om), &sam, &cam);
        v2f m00; m00.x =  cap*cth; m00.y = -sap*cth;
        v2f m01; m01.x = -cam*sth; m01.y = -sam*sth;
        v2f m10; m10.x =  cam*sth; m10.y = -sam*sth;
        v2f m11; m11.x =  cap*cth; m11.y =  sap*cth;
        matp[l][w][0] = m00; matp[l][w][1] = m01;
        matp[l][w][2] = m10; matp[l][w][3] = m11;
    }
    if (tid >= 256) xs[tid - 256] = x[b*(TT*8) + (tid - 256)];

    float wf=0,bfv=0,wi=0,biv=0,wc=0,bcv=0,wo=0,bov=0,c_reg=0,h_reg=0;
    if (tid < HH){
        c_reg = c0[b*HH + tid];  h_reg = h0[b*HH + tid];
        wf=Wf[tid]; bfv=bfp[tid]; wi=Wi[tid]; biv=bip[tid];
        wc=Wc[tid]; bcv=bcp[tid]; wo=Wo[tid]; bov=bop[tid];
    }
    // chain constants for wire cw = tid&3 (h-wires 8+cw), every lane
    const int cw = tid & 3;
    const float WfC=Wf[cw], bfC=bfp[cw], WiC=Wi[cw], biC=bip[cw];
    const float WcC=Wc[cw], bcC=bcp[cw], WoC=Wo[cw], boC=bop[cw];
    float c4 = c0[b*HH + cw];
    const float h_init = h0[b*HH + cw];
    __syncthreads();

    // hoist chain matrices (layer-0, wire 8+cw)
    const v2f M8w0 = matp[0][8+cw][0], M8w1 = matp[0][8+cw][1];
    const v2f M8w2 = matp[0][8+cw][2], M8w3 = matp[0][8+cw][3];

    // t=0 x-wire vvx by threads 128..135
    if (tid >= 128 && tid < 136){
        const int w = tid - 128;
        float sa, ca; sincosf(0.5f*xs[w], &sa, &ca);
        const v2f M00=matp[0][w][0], M01=matp[0][w][1], M10=matp[0][w][2], M11=matp[0][w][3];
        v2f t0v; t0v.x = M00.x*ca + M01.y*sa; t0v.y = M00.y*ca - M01.x*sa;
        v2f t1v; t1v.x = M10.x*ca + M11.y*sa; t1v.y = M10.y*ca - M11.x*sa;
        vvx[w][0] = t0v; vvx[w][1] = t1v;
    }
    // t=0 h-wire vvh, per wave (own-wave write -> read, in-order DS)
    v4f hv0, hv1, hv2, hv3;
    {
        float sa, ca; sincosf(0.5f*h_init, &sa, &ca);
        v4f hw;
        hw.x = M8w0.x*ca + M8w1.y*sa;  hw.y = M8w0.y*ca - M8w1.x*sa;
        hw.z = M8w2.x*ca + M8w3.y*sa;  hw.w = M8w2.y*ca - M8w3.x*sa;
        if (lane < 4) vvh[wave][lane] = hw;
        asm volatile("" ::: "memory");
        hv0 = vvh[wave][0]; hv1 = vvh[wave][1]; hv2 = vvh[wave][2]; hv3 = vvh[wave][3];
    }
    __syncthreads();

    // ---- per-thread constants ----
    const float sg0 = (__builtin_parity(tid & (gM0 & 0x1FFu)) ? -1.f : 1.f);
    const float sg1 = (__builtin_parity(tid & (gM1 & 0x1FFu)) ? -1.f : 1.f);
    const float sg2 = (__builtin_parity(tid & (gM2 & 0x1FFu)) ? -1.f : 1.f);
    const float sg3 = (__builtin_parity(tid & (gM3 & 0x1FFu)) ? -1.f : 1.f);
    // per-config swizzled bases; per-k masks are compile-time XOR constants
    const int bA = (tid << 3) ^ (tid & 31);                                  // cfg A: ^ k
    const int bB = (tid & 7) ^ (((tid >> 3) & 3) << 3) ^ ((tid >> 3) << 6);  // cfg B: ^ 9k
    const int bC = ((tid & 63) ^ ((tid >> 3) & 7)) | ((tid >> 6) << 9);      // cfg C: ^ (k<<6 | (k&3)<<3)
    const int bD = tid ^ ((tid >> 3) & 31);                                  // cfg D: + (k<<9)
    // product-state selectors after F0 (j = (tid<<3)|k): wire w in 2..8 -> tid bit (8-w)^(9-w)
    const int s2 = ((tid>>6) ^ (tid>>7)) & 1;
    const int s3 = ((tid>>5) ^ (tid>>6)) & 1;
    const int s4 = ((tid>>4) ^ (tid>>5)) & 1;
    const int s5 = ((tid>>3) ^ (tid>>4)) & 1;
    const int s6 = ((tid>>2) ^ (tid>>3)) & 1;
    const int s7 = ((tid>>1) ^ (tid>>2)) & 1;
    const int s8 = ( tid     ^ (tid>>1)) & 1;
    const int t8  = (tid >> 8) & 1;
    const int t78 = ((tid>>7) ^ (tid>>8)) & 1;
    const int t0  = tid & 1;
    const v2f* vf = &vvx[0][0];

    v2f amp[8];

    #pragma unroll 1
    for (int t = 0; t < TT; ++t){
        // ---- direct build of post-CNOT0 product state: amp[k] = prod[F0((tid<<3)|k)] ----
        const v2f e2 = vf[ 4+s2], e3 = vf[ 6+s3], e4 = vf[ 8+s4];
        const v2f e5 = vf[10+s5], e6 = vf[12+s6], e7 = vf[14+s7];
        v2f e8; e8.x = s8 ? hv0.z : hv0.x;  e8.y = s8 ? hv0.w : hv0.y;
        const v2f Q  = pk_cmul(pk_cmul(pk_cmul(e2,e3), pk_cmul(e4,e5)),
                               pk_cmul(pk_cmul(e6,e7), e8));
        const v2f v0a = vf[0], v0b = vf[1], v1a = vf[2], v1b = vf[3];
        const v2f ua0 = t8 ? v0b : v0a,  ua1 = t8 ? v0a : v0b;
        const v2f ub0 = t78 ? v1b : v1a, ub1 = t78 ? v1a : v1b;
        const v2f QU0 = pk_cmul(Q, pk_cmul(ua0, ub0));
        const v2f QU1 = pk_cmul(Q, pk_cmul(ua1, ub1));
        v2f v9a; v9a.x = hv1.x; v9a.y = hv1.y;
        v2f v9b; v9b.x = hv1.z; v9b.y = hv1.w;
        const v2f v9s0 = t0 ? v9b : v9a, v9s1 = t0 ? v9a : v9b;
        v2f v10a; v10a.x = hv2.x; v10a.y = hv2.y;
        v2f v10b; v10b.x = hv2.z; v10b.y = hv2.w;
        v2f v11a; v11a.x = hv3.x; v11a.y = hv3.y;
        v2f v11b; v11b.x = hv3.z; v11b.y = hv3.w;
        const v2f P2_0 = pk_cmul(v10a, v11a), P2_1 = pk_cmul(v10a, v11b);
        const v2f P2_2 = pk_cmul(v10b, v11a), P2_3 = pk_cmul(v10b, v11b);
        #pragma unroll
        for (int k = 0; k < 8; ++k){
            const int g = k ^ (k >> 1);
            const v2f base = (k & 1) ? QU1 : QU0;
            const v2f w9   = (g & 4) ? v9s1 : v9s0;
            const v2f p2   = (g&3)==0 ? P2_0 : (g&3)==1 ? P2_1 : (g&3)==2 ? P2_2 : P2_3;
            amp[k] = pk_cmul(pk_cmul(base, w9), p2);
        }

        // ---- 12 layer-1 Rot gates in 4 rounds; T1/T2 wave-local (fence only) ----
        rot3(amp, matp[1], 11);                  // wires 11,10,9 (j bits 0..2)
        #pragma unroll
        for (int k = 0; k < 8; ++k) S[bA ^ k] = amp[k];                 // T1 write (cfg A)
        asm volatile("" ::: "memory");
        #pragma unroll
        for (int k = 0; k < 8; ++k) amp[k] = S[bB ^ (9*k)];             // T1 read (cfg B)
        rot3(amp, matp[1], 8);                   // wires 8,7,6 (j bits 3..5)
        #pragma unroll
        for (int k = 0; k < 8; ++k) S[bB ^ (9*k)] = amp[k];             // T2 write (in place)
        asm volatile("" ::: "memory");
        #pragma unroll
        for (int k = 0; k < 8; ++k) amp[k] = S[bC ^ ((k<<6) | ((k&3)<<3))]; // T2 read (cfg C)
        rot3(amp, matp[1], 5);                   // wires 5,4,3 (j bits 6..8)
        #pragma unroll
        for (int k = 0; k < 8; ++k) S[bC ^ ((k<<6) | ((k&3)<<3))] = amp[k]; // T3 write (in place)
        __syncthreads();                         // barrier 1 (cross-wave transpose)
        #pragma unroll
        for (int k = 0; k < 8; ++k) amp[k] = S[bD + (k<<9)];            // T3 read (cfg D)
        rot3(amp, matp[1], 2);                   // wires 2,1,0 (j bits 9..11)

        // ---- CNOT layer 1 folded into <Z_g>; j = (k<<9)|tid ----
        v2f a01; a01.x = 0.f; a01.y = 0.f;
        v2f a23; a23.x = 0.f; a23.y = 0.f;
        expk<0>(amp, a01, a23);
        float p0 = a01.x * sg0, p1 = a01.y * sg1;
        float p2s = a23.x * sg2, p3 = a23.y * sg3;
        p0 = wsum(p0); p1 = wsum(p1); p2s = wsum(p2s); p3 = wsum(p3);   // lane 63 has sums
        if (lane == 63) red4[wave] = make_float4(p0, p1, p2s, p3);
        // next step's x-wire vvx (readers consumed vvx before T3 barrier; reads of
        // the NEW values happen only after the barrier below)
        if (tid >= 128 && tid < 136){
            const int w  = tid - 128;
            const int tn = (t + 1 < TT) ? t + 1 : t;
            float sa, ca; __sincosf(0.5f*xs[tn*8 + w], &sa, &ca);
            const v2f M00=matp[0][w][0], M01=matp[0][w][1], M10=matp[0][w][2], M11=matp[0][w][3];
            v2f t0v; t0v.x = M00.x*ca + M01.y*sa; t0v.y = M00.y*ca - M01.x*sa;
            v2f t1v; t1v.x = M10.x*ca + M11.y*sa; t1v.y = M10.y*ca - M11.x*sa;
            vvx[w][0] = t0v; vvx[w][1] = t1v;
        }
        __syncthreads();                         // barrier 2 (red4 + vvx visibility)

        // ---- tail: every wave redundantly computes q + its wire's chain (no barrier) ----
        float q0=0.f, q1=0.f, q2=0.f, q3=0.f;
        #pragma unroll
        for (int i = 0; i < 8; ++i){
            const float4 r = red4[i];
            q0 += r.x; q1 += r.y; q2 += r.z; q3 += r.w;
        }
        {
            const float fg = fsig (q0*WfC + bfC);
            const float ig = fsig (q1*WiC + biC);
            const float cg = ftanh(q2*WcC + bcC);
            const float og = fsig (q3*WoC + boC);
            c4 = fg*c4 + ig*cg;
            const float hj = og * ftanh(c4);
            float sa, ca; __sincosf(0.5f*hj, &sa, &ca);
            v4f hw;
            hw.x = M8w0.x*ca + M8w1.y*sa;  hw.y = M8w0.y*ca - M8w1.x*sa;
            hw.z = M8w2.x*ca + M8w3.y*sa;  hw.w = M8w2.y*ca - M8w3.x*sa;
            if (lane < 4) vvh[wave][lane] = hw;          // wave-private slot
            asm volatile("" ::: "memory");
            hv0 = vvh[wave][0]; hv1 = vvh[wave][1];      // own-wave in-order read-back
            hv2 = vvh[wave][2]; hv3 = vvh[wave][3];
        }
        // personal LSTM state for output (threads 0..127)
        if (tid < HH){
            const float fg = fsig (q0*wf + bfv);
            const float ig = fsig (q1*wi + biv);
            const float cg = ftanh(q2*wc + bcv);
            const float og = fsig (q3*wo + bov);
            c_reg = fg*c_reg + ig*cg;
            h_reg = og * ftanh(c_reg);
        }
    }

    if (tid < HH){
        out[b*HH + tid]          = h_reg;
        out[BB*HH + b*HH + tid]  = c_reg;
    }
}

extern "C" void kernel_launch(void* const* d_in, const int* in_sizes, int n_in,
                              void* d_out, int out_size, void* d_ws, size_t ws_size,
                              hipStream_t stream)
{
    (void)in_sizes; (void)n_in; (void)d_ws; (void)ws_size; (void)out_size;
    const float* x  = (const float*)d_in[0];
    const float* h0 = (const float*)d_in[1];
    const float* c0 = (const float*)d_in[2];
    const float* qw = (const float*)d_in[3];
    const float* Wf = (const float*)d_in[4];
    const float* bf = (const float*)d_in[5];
    const float* Wi = (const float*)d_in[6];
    const float* bi = (const float*)d_in[7];
    const float* Wc = (const float*)d_in[8];
    const float* bc = (const float*)d_in[9];
    const float* Wo = (const float*)d_in[10];
    const float* bo = (const float*)d_in[11];
    qlstm_kernel<<<BB, NT, 0, stream>>>(x, h0, c0, qw, Wf, bf, Wi, bi,
                                        Wc, bc, Wo, bo, (float*)d_out);
}

// Round 9
// 108.300 us; speedup vs baseline: 1.6059x; 1.1043x over previous
//
#include <hip/hip_runtime.h>
#include <math.h>

#define NQ 12
#define NS 4096
#define TT 32
#define BB 256
#define HH 128
#define NT 512

typedef float v2f __attribute__((ext_vector_type(2)));
typedef float v4f __attribute__((ext_vector_type(4)));

// ---------- compile-time CNOT-layer permutations (exactly per reference _cnot) ----------
constexpr unsigned cnot_g(unsigned x, int w, int r){
    int pc = 11 - w;                    // control wire w -> bit 11-w
    int pt = 11 - ((w + r) % 12);       // target wire (w+r)%12
    return x ^ (((x >> pc) & 1u) << pt);
}
constexpr unsigned Fperm(unsigned i, int r){      // new[i] = old[Fperm(i,r)]
    unsigned x = i;
    for (int w = 11; w >= 0; --w) x = cnot_g(x, w, r);
    return x;
}
constexpr unsigned Finv(unsigned i, int r){
    unsigned x = i;
    for (int w = 0; w < 12; ++w) x = cnot_g(x, w, r);
    return x;
}
constexpr unsigned F0closed(unsigned i){          // Fperm(.,1) closed form
    return i ^ ((i >> 1) & 0x7FFu) ^ ((i & 1u) << 10) ^ ((i & 1u) << 11);
}
// GF(2)-linear -> basis equality implies equality everywhere (constexpr step-limit safe).
constexpr bool check_all(){
    for (int b = 0; b < NQ; ++b){
        const unsigned e = 1u << b;
        if (F0closed(e) != Fperm(e,1)) return false;
        if (Fperm(Finv(e,1),1) != e) return false;
        if (Fperm(Finv(e,2),2) != e) return false;
    }
    if (F0closed(0u) != 0u || Fperm(0u,1) != 0u || Finv(0u,2) != 0u) return false;
    if (F0closed(0x5A3u) != Fperm(0x5A3u,1)) return false;
    if (Fperm(Finv(0xABCu,2),2) != 0xABCu) return false;
    return true;
}
static_assert(check_all(), "CNOT permutation closed forms wrong");
constexpr unsigned maskM(int k){
    unsigned m = 0;
    for (int b = 0; b < NQ; ++b) m |= ((Finv(1u<<b, 2) >> (11 - k)) & 1u) << b;
    return m;
}
constexpr unsigned gM0 = maskM(0), gM1 = maskM(1), gM2 = maskM(2), gM3 = maskM(3);
constexpr int sgn9(unsigned M, int K){ return __builtin_popcount((unsigned)K & (M >> 9)) & 1; }

// ---------- packed-fp32 complex helpers (VOP3P) ----------
__device__ __forceinline__ v2f pk_cmul(v2f m, v2f a){
    v2f t;
    asm("v_pk_mul_f32 %0, %1, %2 op_sel:[0,0] op_sel_hi:[0,1]"
        : "=v"(t) : "v"(m), "v"(a));
    asm("v_pk_fma_f32 %0, %1, %2, %0 op_sel:[1,1,0] op_sel_hi:[1,0,1] neg_lo:[1,0,0]"
        : "+v"(t) : "v"(m), "v"(a));
    return t;
}
__device__ __forceinline__ v2f pk_cfma(v2f m, v2f a, v2f acc){
    asm("v_pk_fma_f32 %0, %1, %2, %0 op_sel:[0,0,0] op_sel_hi:[0,1,1]"
        : "+v"(acc) : "v"(m), "v"(a));
    asm("v_pk_fma_f32 %0, %1, %2, %0 op_sel:[1,1,0] op_sel_hi:[1,0,1] neg_lo:[1,0,0]"
        : "+v"(acc) : "v"(m), "v"(a));
    return acc;
}
template<int NL, int NH>
__device__ __forceinline__ void pk_accsgn(v2f &acc, v2f ppb){
    if constexpr (NL==0 && NH==0)
        asm("v_pk_add_f32 %0, %1, %0" : "+v"(acc) : "v"(ppb));
    else if constexpr (NL==1 && NH==0)
        asm("v_pk_add_f32 %0, %1, %0 neg_lo:[1,0]" : "+v"(acc) : "v"(ppb));
    else if constexpr (NL==0 && NH==1)
        asm("v_pk_add_f32 %0, %1, %0 neg_hi:[1,0]" : "+v"(acc) : "v"(ppb));
    else
        asm("v_pk_add_f32 %0, %1, %0 neg_lo:[1,0] neg_hi:[1,0]" : "+v"(acc) : "v"(ppb));
}
template<int K>
__device__ __forceinline__ void expk(const v2f* amp, v2f &a01, v2f &a23){
    const float pp = fmaf(amp[K].x, amp[K].x, amp[K].y * amp[K].y);
    v2f ppb; ppb.x = pp; ppb.y = pp;
    pk_accsgn<sgn9(gM0,K), sgn9(gM1,K)>(a01, ppb);
    pk_accsgn<sgn9(gM2,K), sgn9(gM3,K)>(a23, ppb);
    if constexpr (K < 7) expk<K+1>(amp, a01, a23);
}

// ---------- DPP wave-64 sum: result lands in lane 63 (VALU-only, no DS) ----------
template<int C>
__device__ __forceinline__ float dppadd(float v){
    return v + __int_as_float(
        __builtin_amdgcn_update_dpp(0, __float_as_int(v), C, 0xF, 0xF, true));
}
__device__ __forceinline__ float wsum(float v){
    v = dppadd<0x111>(v);   // row_shr:1
    v = dppadd<0x112>(v);   // row_shr:2
    v = dppadd<0x114>(v);   // row_shr:4
    v = dppadd<0x118>(v);   // row_shr:8  -> lane15 of each row16 = row sum
    v = dppadd<0x142>(v);   // row_bcast:15 -> lane31 = rows0+1, lane63 = rows2+3
    v = dppadd<0x143>(v);   // row_bcast:31 -> lane63 = total
    return v;
}

// ---------- rank-5 bank swizzle: slot(j) = j ^ ((j>>3)&0x1F) ----------
// All four per-instruction lane->bank maps have GF(2)-rank 5 -> every b64 access
// is the minimum 2-way (free). Swizzle touches only bits 0..4, so slot bits 9..11
// = j bits 9..11 = wave bits: each wave's 512-slot region is preserved.
// T1 (A->B) and T2 (B->C) keep wave bits identical on both sides => WAVE-LOCAL:
// same-wave DS ops execute in order, so a compiler fence suffices (no barrier).
// T3 (C->D) crosses waves => __syncthreads. read-D(t) vs write-A(t+1) is ordered
// by the red4 barrier (read-D before it, write-A after it).

__device__ __forceinline__ float fsig(float xv){ return __fdividef(1.f, 1.f + __expf(-xv)); }
__device__ __forceinline__ float ftanh(float xv){
    const float e = __expf(-2.f * xv);
    return __fdividef(1.f - e, 1.f + e);
}

// 3 layer-1 Rot gates on the 3 thread-local bits; matrices in REGISTERS
// (WTOP and lb compile-time -> constant register indexing, no scratch)
template<int WTOP>
__device__ __forceinline__ void rot3r(v2f* s, const v2f (&G)[NQ][4]){
    #pragma unroll
    for (int lb = 0; lb < 3; ++lb){
        const v2f M00 = G[WTOP-lb][0], M01 = G[WTOP-lb][1];
        const v2f M10 = G[WTOP-lb][2], M11 = G[WTOP-lb][3];
        #pragma unroll
        for (int k = 0; k < 8; ++k){
            if (k & (1 << lb)) continue;
            const int k1 = k | (1 << lb);
            const v2f a = s[k], b = s[k1];
            s[k]  = pk_cfma(M01, b, pk_cmul(M00, a));
            s[k1] = pk_cfma(M11, b, pk_cmul(M10, a));
        }
    }
}

extern "C" __global__ void __launch_bounds__(NT)
qlstm_kernel(const float* __restrict__ x,  const float* __restrict__ h0,
             const float* __restrict__ c0, const float* __restrict__ qw,
             const float* __restrict__ Wf, const float* __restrict__ bfp,
             const float* __restrict__ Wi, const float* __restrict__ bip,
             const float* __restrict__ Wc, const float* __restrict__ bcp,
             const float* __restrict__ Wo, const float* __restrict__ bop,
             float* __restrict__ out)
{
    __shared__ v2f S[NS];                  // single state buffer (rank-5 swizzled)
    __shared__ v2f matp[2][NQ][4];         // Rot matrices: m00,m01,m10,m11 (re,im)
    __shared__ v2f vvx[8][2];              // x-wire product-state vectors (this step)
    __shared__ v4f vvh[8][4];              // per-WAVE h-wire vectors (wave-private!)
    __shared__ float xs[TT*8];             // preloaded x for this batch element
    __shared__ float4 red4[8];             // per-wave partial expectations

    const int b    = blockIdx.x;
    const int tid  = threadIdx.x;
    const int wave = tid >> 6;
    const int lane = tid & 63;

    // ---- one-time init ----
    if (tid < 2*NQ){
        const int l = tid / NQ, w = tid % NQ;
        const float phi = qw[(l*NQ + w)*3 + 0];
        const float th  = qw[(l*NQ + w)*3 + 1];
        const float om  = qw[(l*NQ + w)*3 + 2];
        float cth, sth, cap, sap, cam, sam;
        sincosf(0.5f*th, &sth, &cth);
        sincosf(0.5f*(phi+om), &sap, &cap);
        sincosf(0.5f*(phi-om), &sam, &cam);
        v2f m00; m00.x =  cap*cth; m00.y = -sap*cth;
        v2f m01; m01.x = -cam*sth; m01.y = -sam*sth;
        v2f m10; m10.x =  cam*sth; m10.y = -sam*sth;
        v2f m11; m11.x =  cap*cth; m11.y =  sap*cth;
        matp[l][w][0] = m00; matp[l][w][1] = m01;
        matp[l][w][2] = m10; matp[l][w][3] = m11;
    }
    if (tid >= 256) xs[tid - 256] = x[b*(TT*8) + (tid - 256)];

    float wf=0,bfv=0,wi=0,biv=0,wc=0,bcv=0,wo=0,bov=0,c_reg=0,h_reg=0;
    if (tid < HH){
        c_reg = c0[b*HH + tid];  h_reg = h0[b*HH + tid];
        wf=Wf[tid]; bfv=bfp[tid]; wi=Wi[tid]; biv=bip[tid];
        wc=Wc[tid]; bcv=bcp[tid]; wo=Wo[tid]; bov=bop[tid];
    }
    // chain constants for wire cw = tid&3 (h-wires 8+cw), every lane
    const int cw = tid & 3;
    const float WfC=Wf[cw], bfC=bfp[cw], WiC=Wi[cw], biC=bip[cw];
    const float WcC=Wc[cw], bcC=bcp[cw], WoC=Wo[cw], boC=bop[cw];
    float c4 = c0[b*HH + cw];
    const float h_init = h0[b*HH + cw];
    __syncthreads();

    // hoist chain matrices (layer-0, wire 8+cw)
    const v2f M8w0 = matp[0][8+cw][0], M8w1 = matp[0][8+cw][1];
    const v2f M8w2 = matp[0][8+cw][2], M8w3 = matp[0][8+cw][3];

    // hoist ALL 12 layer-1 Rot matrices into registers (loop-invariant; 96 VGPR,
    // free at 8 waves/CU which tolerates up to ~256 VGPR)
    v2f G[NQ][4];
    #pragma unroll
    for (int w = 0; w < NQ; ++w)
        #pragma unroll
        for (int m = 0; m < 4; ++m) G[w][m] = matp[1][w][m];

    // t=0 x-wire vvx by threads 128..135
    if (tid >= 128 && tid < 136){
        const int w = tid - 128;
        float sa, ca; sincosf(0.5f*xs[w], &sa, &ca);
        const v2f M00=matp[0][w][0], M01=matp[0][w][1], M10=matp[0][w][2], M11=matp[0][w][3];
        v2f t0v; t0v.x = M00.x*ca + M01.y*sa; t0v.y = M00.y*ca - M01.x*sa;
        v2f t1v; t1v.x = M10.x*ca + M11.y*sa; t1v.y = M10.y*ca - M11.x*sa;
        vvx[w][0] = t0v; vvx[w][1] = t1v;
    }
    // t=0 h-wire vvh, per wave (own-wave write -> read, in-order DS)
    v4f hv0, hv1, hv2, hv3;
    {
        float sa, ca; sincosf(0.5f*h_init, &sa, &ca);
        v4f hw;
        hw.x = M8w0.x*ca + M8w1.y*sa;  hw.y = M8w0.y*ca - M8w1.x*sa;
        hw.z = M8w2.x*ca + M8w3.y*sa;  hw.w = M8w2.y*ca - M8w3.x*sa;
        if (lane < 4) vvh[wave][lane] = hw;
        asm volatile("" ::: "memory");
        hv0 = vvh[wave][0]; hv1 = vvh[wave][1]; hv2 = vvh[wave][2]; hv3 = vvh[wave][3];
    }
    __syncthreads();

    // ---- per-thread constants ----
    const float sg0 = (__builtin_parity(tid & (gM0 & 0x1FFu)) ? -1.f : 1.f);
    const float sg1 = (__builtin_parity(tid & (gM1 & 0x1FFu)) ? -1.f : 1.f);
    const float sg2 = (__builtin_parity(tid & (gM2 & 0x1FFu)) ? -1.f : 1.f);
    const float sg3 = (__builtin_parity(tid & (gM3 & 0x1FFu)) ? -1.f : 1.f);
    // per-config swizzled bases; per-k masks are compile-time XOR constants
    const int bA = (tid << 3) ^ (tid & 31);                                  // cfg A: ^ k
    const int bB = (tid & 7) ^ (((tid >> 3) & 3) << 3) ^ ((tid >> 3) << 6);  // cfg B: ^ 9k
    const int bC = ((tid & 63) ^ ((tid >> 3) & 7)) | ((tid >> 6) << 9);      // cfg C: ^ (k<<6 | (k&3)<<3)
    const int bD = tid ^ ((tid >> 3) & 31);                                  // cfg D: + (k<<9)
    // product-state selectors after F0 (j = (tid<<3)|k): wire w in 2..8 -> tid bit (8-w)^(9-w)
    const int s2 = ((tid>>6) ^ (tid>>7)) & 1;
    const int s3 = ((tid>>5) ^ (tid>>6)) & 1;
    const int s4 = ((tid>>4) ^ (tid>>5)) & 1;
    const int s5 = ((tid>>3) ^ (tid>>4)) & 1;
    const int s6 = ((tid>>2) ^ (tid>>3)) & 1;
    const int s7 = ((tid>>1) ^ (tid>>2)) & 1;
    const int s8 = ( tid     ^ (tid>>1)) & 1;
    const int t8  = (tid >> 8) & 1;
    const int t78 = ((tid>>7) ^ (tid>>8)) & 1;
    const int t0  = tid & 1;
    const v2f* vf = &vvx[0][0];

    v2f amp[8];

    #pragma unroll 1
    for (int t = 0; t < TT; ++t){
        // ---- direct build of post-CNOT0 product state: amp[k] = prod[F0((tid<<3)|k)] ----
        const v2f e2 = vf[ 4+s2], e3 = vf[ 6+s3], e4 = vf[ 8+s4];
        const v2f e5 = vf[10+s5], e6 = vf[12+s6], e7 = vf[14+s7];
        v2f e8; e8.x = s8 ? hv0.z : hv0.x;  e8.y = s8 ? hv0.w : hv0.y;
        const v2f Q  = pk_cmul(pk_cmul(pk_cmul(e2,e3), pk_cmul(e4,e5)),
                               pk_cmul(pk_cmul(e6,e7), e8));
        const v2f v0a = vf[0], v0b = vf[1], v1a = vf[2], v1b = vf[3];
        const v2f ua0 = t8 ? v0b : v0a,  ua1 = t8 ? v0a : v0b;
        const v2f ub0 = t78 ? v1b : v1a, ub1 = t78 ? v1a : v1b;
        const v2f QU0 = pk_cmul(Q, pk_cmul(ua0, ub0));
        const v2f QU1 = pk_cmul(Q, pk_cmul(ua1, ub1));
        v2f v9a; v9a.x = hv1.x; v9a.y = hv1.y;
        v2f v9b; v9b.x = hv1.z; v9b.y = hv1.w;
        const v2f v9s0 = t0 ? v9b : v9a, v9s1 = t0 ? v9a : v9b;
        v2f v10a; v10a.x = hv2.x; v10a.y = hv2.y;
        v2f v10b; v10b.x = hv2.z; v10b.y = hv2.w;
        v2f v11a; v11a.x = hv3.x; v11a.y = hv3.y;
        v2f v11b; v11b.x = hv3.z; v11b.y = hv3.w;
        const v2f P2_0 = pk_cmul(v10a, v11a), P2_1 = pk_cmul(v10a, v11b);
        const v2f P2_2 = pk_cmul(v10b, v11a), P2_3 = pk_cmul(v10b, v11b);
        #pragma unroll
        for (int k = 0; k < 8; ++k){
            const int g = k ^ (k >> 1);
            const v2f base = (k & 1) ? QU1 : QU0;
            const v2f w9   = (g & 4) ? v9s1 : v9s0;
            const v2f p2   = (g&3)==0 ? P2_0 : (g&3)==1 ? P2_1 : (g&3)==2 ? P2_2 : P2_3;
            amp[k] = pk_cmul(pk_cmul(base, w9), p2);
        }

        // ---- 12 layer-1 Rot gates in 4 rounds; T1/T2 wave-local (fence only) ----
        rot3r<11>(amp, G);                       // wires 11,10,9 (j bits 0..2)
        #pragma unroll
        for (int k = 0; k < 8; ++k) S[bA ^ k] = amp[k];                 // T1 write (cfg A)
        asm volatile("" ::: "memory");
        #pragma unroll
        for (int k = 0; k < 8; ++k) amp[k] = S[bB ^ (9*k)];             // T1 read (cfg B)
        rot3r<8>(amp, G);                        // wires 8,7,6 (j bits 3..5)
        #pragma unroll
        for (int k = 0; k < 8; ++k) S[bB ^ (9*k)] = amp[k];             // T2 write (in place)
        asm volatile("" ::: "memory");
        #pragma unroll
        for (int k = 0; k < 8; ++k) amp[k] = S[bC ^ ((k<<6) | ((k&3)<<3))]; // T2 read (cfg C)
        rot3r<5>(amp, G);                        // wires 5,4,3 (j bits 6..8)
        #pragma unroll
        for (int k = 0; k < 8; ++k) S[bC ^ ((k<<6) | ((k&3)<<3))] = amp[k]; // T3 write (in place)
        __syncthreads();                         // barrier 1 (cross-wave transpose)
        #pragma unroll
        for (int k = 0; k < 8; ++k) amp[k] = S[bD + (k<<9)];            // T3 read (cfg D)
        rot3r<2>(amp, G);                        // wires 2,1,0 (j bits 9..11)

        // ---- CNOT layer 1 folded into <Z_g>; j = (k<<9)|tid ----
        v2f a01; a01.x = 0.f; a01.y = 0.f;
        v2f a23; a23.x = 0.f; a23.y = 0.f;
        expk<0>(amp, a01, a23);
        float p0 = a01.x * sg0, p1 = a01.y * sg1;
        float p2s = a23.x * sg2, p3 = a23.y * sg3;
        p0 = wsum(p0); p1 = wsum(p1); p2s = wsum(p2s); p3 = wsum(p3);   // lane 63 has sums
        if (lane == 63) red4[wave] = make_float4(p0, p1, p2s, p3);
        // next step's x-wire vvx (readers consumed vvx before T3 barrier; reads of
        // the NEW values happen only after the barrier below)
        if (tid >= 128 && tid < 136){
            const int w  = tid - 128;
            const int tn = (t + 1 < TT) ? t + 1 : t;
            float sa, ca; __sincosf(0.5f*xs[tn*8 + w], &sa, &ca);
            const v2f M00=matp[0][w][0], M01=matp[0][w][1], M10=matp[0][w][2], M11=matp[0][w][3];
            v2f t0v; t0v.x = M00.x*ca + M01.y*sa; t0v.y = M00.y*ca - M01.x*sa;
            v2f t1v; t1v.x = M10.x*ca + M11.y*sa; t1v.y = M10.y*ca - M11.x*sa;
            vvx[w][0] = t0v; vvx[w][1] = t1v;
        }
        __syncthreads();                         // barrier 2 (red4 + vvx visibility)

        // ---- tail: every wave redundantly computes q + its wire's chain (no barrier) ----
        float q0=0.f, q1=0.f, q2=0.f, q3=0.f;
        #pragma unroll
        for (int i = 0; i < 8; ++i){
            const float4 r = red4[i];
            q0 += r.x; q1 += r.y; q2 += r.z; q3 += r.w;
        }
        {
            const float fg = fsig (q0*WfC + bfC);
            const float ig = fsig (q1*WiC + biC);
            const float cg = ftanh(q2*WcC + bcC);
            const float og = fsig (q3*WoC + boC);
            c4 = fg*c4 + ig*cg;
            const float hj = og * ftanh(c4);
            float sa, ca; __sincosf(0.5f*hj, &sa, &ca);
            v4f hw;
            hw.x = M8w0.x*ca + M8w1.y*sa;  hw.y = M8w0.y*ca - M8w1.x*sa;
            hw.z = M8w2.x*ca + M8w3.y*sa;  hw.w = M8w2.y*ca - M8w3.x*sa;
            if (lane < 4) vvh[wave][lane] = hw;          // wave-private slot
            asm volatile("" ::: "memory");
            hv0 = vvh[wave][0]; hv1 = vvh[wave][1];      // own-wave in-order read-back
            hv2 = vvh[wave][2]; hv3 = vvh[wave][3];
        }
        // personal LSTM state for output (threads 0..127)
        if (tid < HH){
            const float fg = fsig (q0*wf + bfv);
            const float ig = fsig (q1*wi + biv);
            const float cg = ftanh(q2*wc + bcv);
            const float og = fsig (q3*wo + bov);
            c_reg = fg*c_reg + ig*cg;
            h_reg = og * ftanh(c_reg);
        }
    }

    if (tid < HH){
        out[b*HH + tid]          = h_reg;
        out[BB*HH + b*HH + tid]  = c_reg;
    }
}

extern "C" void kernel_launch(void* const* d_in, const int* in_sizes, int n_in,
                              void* d_out, int out_size, void* d_ws, size_t ws_size,
                              hipStream_t stream)
{
    (void)in_sizes; (void)n_in; (void)d_ws; (void)ws_size; (void)out_size;
    const float* x  = (const float*)d_in[0];
    const float* h0 = (const float*)d_in[1];
    const float* c0 = (const float*)d_in[2];
    const float* qw = (const float*)d_in[3];
    const float* Wf = (const float*)d_in[4];
    const float* bf = (const float*)d_in[5];
    const float* Wi = (const float*)d_in[6];
    const float* bi = (const float*)d_in[7];
    const float* Wc = (const float*)d_in[8];
    const float* bc = (const float*)d_in[9];
    const float* Wo = (const float*)d_in[10];
    const float* bo = (const float*)d_in[11];
    qlstm_kernel<<<BB, NT, 0, stream>>>(x, h0, c0, qw, Wf, bf, Wi, bi,
                                        Wc, bc, Wo, bo, (float*)d_out);
}

// Round 10
// 104.109 us; speedup vs baseline: 1.6706x; 1.0403x over previous
//
#include <hip/hip_runtime.h>
#include <math.h>

#define NQ 12
#define NS 4096
#define TT 32
#define BB 256
#define HH 128
#define NT 512

typedef float v2f __attribute__((ext_vector_type(2)));
typedef float v4f __attribute__((ext_vector_type(4)));

// ---------- compile-time CNOT-layer permutations (exactly per reference _cnot) ----------
constexpr unsigned cnot_g(unsigned x, int w, int r){
    int pc = 11 - w;                    // control wire w -> bit 11-w
    int pt = 11 - ((w + r) % 12);       // target wire (w+r)%12
    return x ^ (((x >> pc) & 1u) << pt);
}
constexpr unsigned Fperm(unsigned i, int r){      // new[i] = old[Fperm(i,r)]
    unsigned x = i;
    for (int w = 11; w >= 0; --w) x = cnot_g(x, w, r);
    return x;
}
constexpr unsigned Finv(unsigned i, int r){
    unsigned x = i;
    for (int w = 0; w < 12; ++w) x = cnot_g(x, w, r);
    return x;
}
constexpr unsigned F0closed(unsigned i){          // Fperm(.,1) closed form
    return i ^ ((i >> 1) & 0x7FFu) ^ ((i & 1u) << 10) ^ ((i & 1u) << 11);
}
// GF(2)-linear -> basis equality implies equality everywhere (constexpr step-limit safe).
constexpr bool check_all(){
    for (int b = 0; b < NQ; ++b){
        const unsigned e = 1u << b;
        if (F0closed(e) != Fperm(e,1)) return false;
        if (Fperm(Finv(e,1),1) != e) return false;
        if (Fperm(Finv(e,2),2) != e) return false;
    }
    if (F0closed(0u) != 0u || Fperm(0u,1) != 0u || Finv(0u,2) != 0u) return false;
    if (F0closed(0x5A3u) != Fperm(0x5A3u,1)) return false;
    if (Fperm(Finv(0xABCu,2),2) != 0xABCu) return false;
    return true;
}
static_assert(check_all(), "CNOT permutation closed forms wrong");
constexpr unsigned maskM(int k){
    unsigned m = 0;
    for (int b = 0; b < NQ; ++b) m |= ((Finv(1u<<b, 2) >> (11 - k)) & 1u) << b;
    return m;
}
constexpr unsigned gM0 = maskM(0), gM1 = maskM(1), gM2 = maskM(2), gM3 = maskM(3);
constexpr int sgn9(unsigned M, int K){ return __builtin_popcount((unsigned)K & (M >> 9)) & 1; }

// ---------- packed-fp32 complex helpers (VOP3P) ----------
__device__ __forceinline__ v2f pk_cmul(v2f m, v2f a){
    v2f t;
    asm("v_pk_mul_f32 %0, %1, %2 op_sel:[0,0] op_sel_hi:[0,1]"
        : "=v"(t) : "v"(m), "v"(a));
    asm("v_pk_fma_f32 %0, %1, %2, %0 op_sel:[1,1,0] op_sel_hi:[1,0,1] neg_lo:[1,0,0]"
        : "+v"(t) : "v"(m), "v"(a));
    return t;
}
template<int NL, int NH>
__device__ __forceinline__ void pk_accsgn(v2f &acc, v2f ppb){
    if constexpr (NL==0 && NH==0)
        asm("v_pk_add_f32 %0, %1, %0" : "+v"(acc) : "v"(ppb));
    else if constexpr (NL==1 && NH==0)
        asm("v_pk_add_f32 %0, %1, %0 neg_lo:[1,0]" : "+v"(acc) : "v"(ppb));
    else if constexpr (NL==0 && NH==1)
        asm("v_pk_add_f32 %0, %1, %0 neg_hi:[1,0]" : "+v"(acc) : "v"(ppb));
    else
        asm("v_pk_add_f32 %0, %1, %0 neg_lo:[1,0] neg_hi:[1,0]" : "+v"(acc) : "v"(ppb));
}
template<int K>
__device__ __forceinline__ void expk(const v2f* amp, v2f &a01, v2f &a23){
    const float pp = fmaf(amp[K].x, amp[K].x, amp[K].y * amp[K].y);
    v2f ppb; ppb.x = pp; ppb.y = pp;
    pk_accsgn<sgn9(gM0,K), sgn9(gM1,K)>(a01, ppb);
    pk_accsgn<sgn9(gM2,K), sgn9(gM3,K)>(a23, ppb);
    if constexpr (K < 7) expk<K+1>(amp, a01, a23);
}

// ---------- DPP wave-64 sum: result lands in lane 63 (VALU-only, no DS) ----------
template<int C>
__device__ __forceinline__ float dppadd(float v){
    return v + __int_as_float(
        __builtin_amdgcn_update_dpp(0, __float_as_int(v), C, 0xF, 0xF, true));
}
__device__ __forceinline__ float wsum(float v){
    v = dppadd<0x111>(v);   // row_shr:1
    v = dppadd<0x112>(v);   // row_shr:2
    v = dppadd<0x114>(v);   // row_shr:4
    v = dppadd<0x118>(v);   // row_shr:8  -> lane15 of each row16 = row sum
    v = dppadd<0x142>(v);   // row_bcast:15 -> lane31 = rows0+1, lane63 = rows2+3
    v = dppadd<0x143>(v);   // row_bcast:31 -> lane63 = total
    return v;
}

// ---------- rank-5 bank swizzle: slot(j) = j ^ ((j>>3)&0x1F) ----------
// (validated R7-R9: SQ_LDS_BANK_CONFLICT ~ 0; T1/T2 wave-local, T3 cross-wave)

__device__ __forceinline__ float fsig(float xv){ return __fdividef(1.f, 1.f + __expf(-xv)); }
__device__ __forceinline__ float ftanh(float xv){
    const float e = __expf(-2.f * xv);
    return __fdividef(1.f - e, 1.f + e);
}

// 3 layer-1 RY gates on the 3 thread-local bits (RZ phases folded out):
// RY(th): s[k] = c*a - s*b ; s[k1] = s*a + c*b, c/s REAL -> 4 VOP3P per pair.
template<int WTOP>
__device__ __forceinline__ void rot3ry(v2f* s, const v2f* G){
    #pragma unroll
    for (int lb = 0; lb < 3; ++lb){
        const float cw = G[WTOP-lb].x, sw = G[WTOP-lb].y;
        #pragma unroll
        for (int k = 0; k < 8; ++k){
            if (k & (1 << lb)) continue;
            const int k1 = k | (1 << lb);
            const v2f a = s[k], b = s[k1];
            s[k]  = a*cw - b*sw;
            s[k1] = a*sw + b*cw;
        }
    }
}

extern "C" __global__ void __launch_bounds__(NT)
qlstm_kernel(const float* __restrict__ x,  const float* __restrict__ h0,
             const float* __restrict__ c0, const float* __restrict__ qw,
             const float* __restrict__ Wf, const float* __restrict__ bfp,
             const float* __restrict__ Wi, const float* __restrict__ bip,
             const float* __restrict__ Wc, const float* __restrict__ bcp,
             const float* __restrict__ Wo, const float* __restrict__ bop,
             float* __restrict__ out)
{
    __shared__ v2f S[NS];                  // single state buffer (rank-5 swizzled)
    __shared__ v2f matp[NQ][4];            // layer-0 Rot matrices (full, for vv build)
    __shared__ v2f vvx[8][2];              // x-wire product-state vectors (this step)
    __shared__ v4f vvh[8][4];              // per-WAVE h-wire vectors (wave-private)
    __shared__ float xs[TT*8];             // preloaded x for this batch element
    __shared__ float4 red4[8];             // per-wave partial expectations
    __shared__ float4 qh[TT];              // q history for epilogue LSTM scan

    const int b    = blockIdx.x;
    const int tid  = threadIdx.x;
    const int wave = tid >> 6;
    const int lane = tid & 63;

    // ---- one-time init: layer-0 matrices ----
    if (tid < NQ){
        const int w = tid;
        const float phi = qw[w*3 + 0];
        const float th  = qw[w*3 + 1];
        const float om  = qw[w*3 + 2];
        float cth, sth, cap, sap, cam, sam;
        sincosf(0.5f*th, &sth, &cth);
        sincosf(0.5f*(phi+om), &sap, &cap);
        sincosf(0.5f*(phi-om), &sam, &cam);
        v2f m00; m00.x =  cap*cth; m00.y = -sap*cth;
        v2f m01; m01.x = -cam*sth; m01.y = -sam*sth;
        v2f m10; m10.x =  cam*sth; m10.y = -sam*sth;
        v2f m11; m11.x =  cap*cth; m11.y =  sap*cth;
        matp[w][0] = m00; matp[w][1] = m01;
        matp[w][2] = m10; matp[w][3] = m11;
    }
    if (tid >= 256) xs[tid - 256] = x[b*(TT*8) + (tid - 256)];

    // ---- layer-1 per-thread constants: RY (c,s), Dphi folds ----
    // wire w <-> j bit 11-w; j = (tid<<3)|k: wires 0..8 -> tid bits 8..0; wires 9,10,11 -> k bits 2,1,0
    v2f G[NQ];
    #pragma unroll
    for (int w = 0; w < NQ; ++w){
        float cg, sg; sincosf(0.5f*qw[(NQ + w)*3 + 1], &sg, &cg);
        G[w].x = cg; G[w].y = sg;
    }
    v2f Zphi;
    {
        float A = 0.f;
        #pragma unroll
        for (int w = 0; w <= 8; ++w){
            const float ph = qw[(NQ + w)*3 + 0];
            A += ((tid >> (8 - w)) & 1) ? ph : -ph;
        }
        float sa, ca; sincosf(0.5f*A, &sa, &ca);
        Zphi.x = ca; Zphi.y = sa;                 // e^{iA/?}: A already the half-sum
    }
    v2f dd[8];
    {
        const float p9  = qw[(NQ + 9)*3 + 0];
        const float p10 = qw[(NQ +10)*3 + 0];
        const float p11 = qw[(NQ +11)*3 + 0];
        #pragma unroll
        for (int k = 0; k < 8; ++k){
            const float Bq = 0.5f*(((k&4)? p9 : -p9) + ((k&2)? p10 : -p10) + ((k&1)? p11 : -p11));
            float sb, cb; sincosf(Bq, &sb, &cb);
            dd[k].x = cb; dd[k].y = sb;
        }
    }

    // chain constants for wire cw = tid&3 (h-wires 8+cw), every lane (per-wave-redundant tail)
    const int cw = tid & 3;
    const float WfC=Wf[cw], bfC=bfp[cw], WiC=Wi[cw], biC=bip[cw];
    const float WcC=Wc[cw], bcC=bcp[cw], WoC=Wo[cw], boC=bop[cw];
    float c4 = c0[b*HH + cw];
    const float h_init = h0[b*HH + cw];
    __syncthreads();

    // hoist chain matrices (layer-0, wire 8+cw)
    const v2f M8w0 = matp[8+cw][0], M8w1 = matp[8+cw][1];
    const v2f M8w2 = matp[8+cw][2], M8w3 = matp[8+cw][3];

    // t=0 x-wire vvx by threads 128..135
    if (tid >= 128 && tid < 136){
        const int w = tid - 128;
        float sa, ca; sincosf(0.5f*xs[w], &sa, &ca);
        const v2f M00=matp[w][0], M01=matp[w][1], M10=matp[w][2], M11=matp[w][3];
        v2f t0v; t0v.x = M00.x*ca + M01.y*sa; t0v.y = M00.y*ca - M01.x*sa;
        v2f t1v; t1v.x = M10.x*ca + M11.y*sa; t1v.y = M10.y*ca - M11.x*sa;
        vvx[w][0] = t0v; vvx[w][1] = t1v;
    }
    // t=0 h-wire vvh, per wave (own-wave write -> read, in-order DS)
    v4f hv0, hv1, hv2, hv3;
    {
        float sa, ca; sincosf(0.5f*h_init, &sa, &ca);
        v4f hw;
        hw.x = M8w0.x*ca + M8w1.y*sa;  hw.y = M8w0.y*ca - M8w1.x*sa;
        hw.z = M8w2.x*ca + M8w3.y*sa;  hw.w = M8w2.y*ca - M8w3.x*sa;
        if (lane < 4) vvh[wave][lane] = hw;
        asm volatile("" ::: "memory");
        hv0 = vvh[wave][0]; hv1 = vvh[wave][1]; hv2 = vvh[wave][2]; hv3 = vvh[wave][3];
    }
    __syncthreads();

    // ---- per-thread constants ----
    const float sg0 = (__builtin_parity(tid & (gM0 & 0x1FFu)) ? -1.f : 1.f);
    const float sg1 = (__builtin_parity(tid & (gM1 & 0x1FFu)) ? -1.f : 1.f);
    const float sg2 = (__builtin_parity(tid & (gM2 & 0x1FFu)) ? -1.f : 1.f);
    const float sg3 = (__builtin_parity(tid & (gM3 & 0x1FFu)) ? -1.f : 1.f);
    const int bA = (tid << 3) ^ (tid & 31);                                  // cfg A: ^ k
    const int bB = (tid & 7) ^ (((tid >> 3) & 3) << 3) ^ ((tid >> 3) << 6);  // cfg B: ^ 9k
    const int bC = ((tid & 63) ^ ((tid >> 3) & 7)) | ((tid >> 6) << 9);      // cfg C: ^ (k<<6 | (k&3)<<3)
    const int bD = tid ^ ((tid >> 3) & 31);                                  // cfg D: + (k<<9)
    const int s2 = ((tid>>6) ^ (tid>>7)) & 1;
    const int s3 = ((tid>>5) ^ (tid>>6)) & 1;
    const int s4 = ((tid>>4) ^ (tid>>5)) & 1;
    const int s5 = ((tid>>3) ^ (tid>>4)) & 1;
    const int s6 = ((tid>>2) ^ (tid>>3)) & 1;
    const int s7 = ((tid>>1) ^ (tid>>2)) & 1;
    const int s8 = ( tid     ^ (tid>>1)) & 1;
    const int t8  = (tid >> 8) & 1;
    const int t78 = ((tid>>7) ^ (tid>>8)) & 1;
    const int t0  = tid & 1;
    const v2f* vf = &vvx[0][0];

    v2f amp[8];

    #pragma unroll 1
    for (int t = 0; t < TT; ++t){
        // ---- build post-CNOT0 product state x Dphi: amp[k] = prod[F0((tid<<3)|k)] * Zphi * dd[k] ----
        const v2f e2 = vf[ 4+s2], e3 = vf[ 6+s3], e4 = vf[ 8+s4];
        const v2f e5 = vf[10+s5], e6 = vf[12+s6], e7 = vf[14+s7];
        v2f e8; e8.x = s8 ? hv0.z : hv0.x;  e8.y = s8 ? hv0.w : hv0.y;
        const v2f Q  = pk_cmul(pk_cmul(pk_cmul(e2,e3), pk_cmul(e4,e5)),
                               pk_cmul(pk_cmul(e6,e7), pk_cmul(e8, Zphi)));
        const v2f v0a = vf[0], v0b = vf[1], v1a = vf[2], v1b = vf[3];
        const v2f ua0 = t8 ? v0b : v0a,  ua1 = t8 ? v0a : v0b;
        const v2f ub0 = t78 ? v1b : v1a, ub1 = t78 ? v1a : v1b;
        const v2f QU0 = pk_cmul(Q, pk_cmul(ua0, ub0));
        const v2f QU1 = pk_cmul(Q, pk_cmul(ua1, ub1));
        v2f v9a; v9a.x = hv1.x; v9a.y = hv1.y;
        v2f v9b; v9b.x = hv1.z; v9b.y = hv1.w;
        const v2f v9s0 = t0 ? v9b : v9a, v9s1 = t0 ? v9a : v9b;
        v2f v10a; v10a.x = hv2.x; v10a.y = hv2.y;
        v2f v10b; v10b.x = hv2.z; v10b.y = hv2.w;
        v2f v11a; v11a.x = hv3.x; v11a.y = hv3.y;
        v2f v11b; v11b.x = hv3.z; v11b.y = hv3.w;
        const v2f P2_0 = pk_cmul(v10a, v11a), P2_1 = pk_cmul(v10a, v11b);
        const v2f P2_2 = pk_cmul(v10b, v11a), P2_3 = pk_cmul(v10b, v11b);
        #pragma unroll
        for (int k = 0; k < 8; ++k){
            const int g = k ^ (k >> 1);
            const v2f base = (k & 1) ? QU1 : QU0;
            const v2f w9   = (g & 4) ? v9s1 : v9s0;
            const v2f p2   = (g&3)==0 ? P2_0 : (g&3)==1 ? P2_1 : (g&3)==2 ? P2_2 : P2_3;
            amp[k] = pk_cmul(pk_cmul(base, w9), pk_cmul(p2, dd[k]));
        }

        // ---- 12 layer-1 RY gates in 4 rounds; T1/T2 wave-local (fence only) ----
        rot3ry<11>(amp, G);                      // wires 11,10,9 (j bits 0..2)
        #pragma unroll
        for (int k = 0; k < 8; ++k) S[bA ^ k] = amp[k];                 // T1 write (cfg A)
        asm volatile("" ::: "memory");
        #pragma unroll
        for (int k = 0; k < 8; ++k) amp[k] = S[bB ^ (9*k)];             // T1 read (cfg B)
        rot3ry<8>(amp, G);                       // wires 8,7,6 (j bits 3..5)
        #pragma unroll
        for (int k = 0; k < 8; ++k) S[bB ^ (9*k)] = amp[k];             // T2 write (in place)
        asm volatile("" ::: "memory");
        #pragma unroll
        for (int k = 0; k < 8; ++k) amp[k] = S[bC ^ ((k<<6) | ((k&3)<<3))]; // T2 read (cfg C)
        rot3ry<5>(amp, G);                       // wires 5,4,3 (j bits 6..8)
        #pragma unroll
        for (int k = 0; k < 8; ++k) S[bC ^ ((k<<6) | ((k&3)<<3))] = amp[k]; // T3 write (in place)
        __syncthreads();                         // barrier 1 (cross-wave transpose)
        #pragma unroll
        for (int k = 0; k < 8; ++k) amp[k] = S[bD + (k<<9)];            // T3 read (cfg D)
        rot3ry<2>(amp, G);                       // wires 2,1,0 (j bits 9..11)

        // ---- CNOT layer 1 folded into <Z_g>; j = (k<<9)|tid ----
        v2f a01; a01.x = 0.f; a01.y = 0.f;
        v2f a23; a23.x = 0.f; a23.y = 0.f;
        expk<0>(amp, a01, a23);
        float p0 = a01.x * sg0, p1 = a01.y * sg1;
        float p2s = a23.x * sg2, p3 = a23.y * sg3;
        p0 = wsum(p0); p1 = wsum(p1); p2s = wsum(p2s); p3 = wsum(p3);   // lane 63 has sums
        if (lane == 63) red4[wave] = make_float4(p0, p1, p2s, p3);
        // next step's x-wire vvx (consumed pre-T3-barrier; new values read post-barrier2)
        if (tid >= 128 && tid < 136){
            const int w  = tid - 128;
            const int tn = (t + 1 < TT) ? t + 1 : t;
            float sa, ca; __sincosf(0.5f*xs[tn*8 + w], &sa, &ca);
            const v2f M00=matp[w][0], M01=matp[w][1], M10=matp[w][2], M11=matp[w][3];
            v2f t0v; t0v.x = M00.x*ca + M01.y*sa; t0v.y = M00.y*ca - M01.x*sa;
            v2f t1v; t1v.x = M10.x*ca + M11.y*sa; t1v.y = M10.y*ca - M11.x*sa;
            vvx[w][0] = t0v; vvx[w][1] = t1v;
        }
        __syncthreads();                         // barrier 2 (red4 + vvx visibility)

        // ---- tail: every wave redundantly computes q + its wire's chain (no barrier) ----
        float q0=0.f, q1=0.f, q2=0.f, q3=0.f;
        #pragma unroll
        for (int i = 0; i < 8; ++i){
            const float4 r = red4[i];
            q0 += r.x; q1 += r.y; q2 += r.z; q3 += r.w;
        }
        if (tid == 0) qh[t] = make_float4(q0, q1, q2, q3);   // history for epilogue
        {
            const float fg = fsig (q0*WfC + bfC);
            const float ig = fsig (q1*WiC + biC);
            const float cg = ftanh(q2*WcC + bcC);
            const float og = fsig (q3*WoC + boC);
            c4 = fg*c4 + ig*cg;
            const float hj = og * ftanh(c4);
            float sa, ca; __sincosf(0.5f*hj, &sa, &ca);
            v4f hw;
            hw.x = M8w0.x*ca + M8w1.y*sa;  hw.y = M8w0.y*ca - M8w1.x*sa;
            hw.z = M8w2.x*ca + M8w3.y*sa;  hw.w = M8w2.y*ca - M8w3.x*sa;
            if (lane < 4) vvh[wave][lane] = hw;          // wave-private slot
            asm volatile("" ::: "memory");
            hv0 = vvh[wave][0]; hv1 = vvh[wave][1];      // own-wave in-order read-back
            hv2 = vvh[wave][2]; hv3 = vvh[wave][3];
        }
    }

    // ---- epilogue: per-channel LSTM scan over the q history (parallel over H) ----
    __syncthreads();
    if (tid < HH){
        const float wfE=Wf[tid], bfE=bfp[tid], wiE=Wi[tid], biE=bip[tid];
        const float wcE=Wc[tid], bcE=bcp[tid], woE=Wo[tid], boE=bop[tid];
        float cc = c0[b*HH + tid];
        float hh = 0.f;
        #pragma unroll 1
        for (int t = 0; t < TT; ++t){
            const float4 q = qh[t];
            const float fg = fsig (q.x*wfE + bfE);
            const float ig = fsig (q.y*wiE + biE);
            const float cg = ftanh(q.z*wcE + bcE);
            const float og = fsig (q.w*woE + boE);
            cc = fg*cc + ig*cg;
            hh = og * ftanh(cc);
        }
        out[b*HH + tid]         = hh;
        out[BB*HH + b*HH + tid] = cc;
    }
}

extern "C" void kernel_launch(void* const* d_in, const int* in_sizes, int n_in,
                              void* d_out, int out_size, void* d_ws, size_t ws_size,
                              hipStream_t stream)
{
    (void)in_sizes; (void)n_in; (void)d_ws; (void)ws_size; (void)out_size;
    const float* x  = (const float*)d_in[0];
    const float* h0 = (const float*)d_in[1];
    const float* c0 = (const float*)d_in[2];
    const float* qw = (const float*)d_in[3];
    const float* Wf = (const float*)d_in[4];
    const float* bf = (const float*)d_in[5];
    const float* Wi = (const float*)d_in[6];
    const float* bi = (const float*)d_in[7];
    const float* Wc = (const float*)d_in[8];
    const float* bc = (const float*)d_in[9];
    const float* Wo = (const float*)d_in[10];
    const float* bo = (const float*)d_in[11];
    qlstm_kernel<<<BB, NT, 0, stream>>>(x, h0, c0, qw, Wf, bf, Wi, bi,
                                        Wc, bc, Wo, bo, (float*)d_out);
}

// Round 11
// 93.062 us; speedup vs baseline: 1.8689x; 1.1187x over previous
//
#include <hip/hip_runtime.h>
#include <math.h>

#define NQ 12
#define NS 4096
#define TT 32
#define BB 256
#define HH 128
#define NT 512

typedef float v2f __attribute__((ext_vector_type(2)));
typedef float v4f __attribute__((ext_vector_type(4)));

// ---------- compile-time CNOT-layer permutations (exactly per reference _cnot) ----------
constexpr unsigned cnot_g(unsigned x, int w, int r){
    int pc = 11 - w;                    // control wire w -> bit 11-w
    int pt = 11 - ((w + r) % 12);       // target wire (w+r)%12
    return x ^ (((x >> pc) & 1u) << pt);
}
constexpr unsigned Fperm(unsigned i, int r){      // new[i] = old[Fperm(i,r)]
    unsigned x = i;
    for (int w = 11; w >= 0; --w) x = cnot_g(x, w, r);
    return x;
}
constexpr unsigned Finv(unsigned i, int r){
    unsigned x = i;
    for (int w = 0; w < 12; ++w) x = cnot_g(x, w, r);
    return x;
}
constexpr unsigned F0closed(unsigned i){          // Fperm(.,1) closed form
    return i ^ ((i >> 1) & 0x7FFu) ^ ((i & 1u) << 10) ^ ((i & 1u) << 11);
}
// GF(2)-linear -> basis equality implies equality everywhere (constexpr step-limit safe).
constexpr bool check_all(){
    for (int b = 0; b < NQ; ++b){
        const unsigned e = 1u << b;
        if (F0closed(e) != Fperm(e,1)) return false;
        if (Fperm(Finv(e,1),1) != e) return false;
        if (Fperm(Finv(e,2),2) != e) return false;
    }
    if (F0closed(0u) != 0u || Fperm(0u,1) != 0u || Finv(0u,2) != 0u) return false;
    if (F0closed(0x5A3u) != Fperm(0x5A3u,1)) return false;
    if (Fperm(Finv(0xABCu,2),2) != 0xABCu) return false;
    return true;
}
static_assert(check_all(), "CNOT permutation closed forms wrong");
constexpr unsigned maskM(int k){
    unsigned m = 0;
    for (int b = 0; b < NQ; ++b) m |= ((Finv(1u<<b, 2) >> (11 - k)) & 1u) << b;
    return m;
}
constexpr unsigned gM0 = maskM(0), gM1 = maskM(1), gM2 = maskM(2), gM3 = maskM(3);
constexpr int sgn9(unsigned M, int K){ return __builtin_popcount((unsigned)K & (M >> 9)) & 1; }

// ---------- packed-fp32 complex helpers (VOP3P) ----------
__device__ __forceinline__ v2f pk_cmul(v2f m, v2f a){
    v2f t;
    asm("v_pk_mul_f32 %0, %1, %2 op_sel:[0,0] op_sel_hi:[0,1]"
        : "=v"(t) : "v"(m), "v"(a));
    asm("v_pk_fma_f32 %0, %1, %2, %0 op_sel:[1,1,0] op_sel_hi:[1,0,1] neg_lo:[1,0,0]"
        : "+v"(t) : "v"(m), "v"(a));
    return t;
}
template<int NL, int NH>
__device__ __forceinline__ void pk_accsgn(v2f &acc, v2f ppb){
    if constexpr (NL==0 && NH==0)
        asm("v_pk_add_f32 %0, %1, %0" : "+v"(acc) : "v"(ppb));
    else if constexpr (NL==1 && NH==0)
        asm("v_pk_add_f32 %0, %1, %0 neg_lo:[1,0]" : "+v"(acc) : "v"(ppb));
    else if constexpr (NL==0 && NH==1)
        asm("v_pk_add_f32 %0, %1, %0 neg_hi:[1,0]" : "+v"(acc) : "v"(ppb));
    else
        asm("v_pk_add_f32 %0, %1, %0 neg_lo:[1,0] neg_hi:[1,0]" : "+v"(acc) : "v"(ppb));
}
template<int K>
__device__ __forceinline__ void expk(const v2f* amp, v2f &a01, v2f &a23){
    const float pp = fmaf(amp[K].x, amp[K].x, amp[K].y * amp[K].y);
    v2f ppb; ppb.x = pp; ppb.y = pp;
    pk_accsgn<sgn9(gM0,K), sgn9(gM1,K)>(a01, ppb);
    pk_accsgn<sgn9(gM2,K), sgn9(gM3,K)>(a23, ppb);
    if constexpr (K < 7) expk<K+1>(amp, a01, a23);
}

// ---------- DPP helpers (VALU-only cross-lane) ----------
template<int C>
__device__ __forceinline__ float dppadd(float v){
    return v + __int_as_float(
        __builtin_amdgcn_update_dpp(0, __float_as_int(v), C, 0xF, 0xF, true));
}
__device__ __forceinline__ float wsum(float v){
    v = dppadd<0x111>(v);   // row_shr:1
    v = dppadd<0x112>(v);   // row_shr:2
    v = dppadd<0x114>(v);   // row_shr:4
    v = dppadd<0x118>(v);   // row_shr:8  -> lane15 of each row16 = row sum
    v = dppadd<0x142>(v);   // row_bcast:15 -> lane31 = rows0+1, lane63 = rows2+3
    v = dppadd<0x143>(v);   // row_bcast:31 -> lane63 = total
    return v;
}
// quad_perm broadcast: every lane gets quad-lane J's value (ctrl = J*0x55)
template<int CTRL>
__device__ __forceinline__ float qpermf(float v){
    return __int_as_float(
        __builtin_amdgcn_update_dpp(0, __float_as_int(v), CTRL, 0xF, 0xF, true));
}
template<int CTRL>
__device__ __forceinline__ v4f qperm4(v4f v){
    v4f r;
    r.x = qpermf<CTRL>(v.x); r.y = qpermf<CTRL>(v.y);
    r.z = qpermf<CTRL>(v.z); r.w = qpermf<CTRL>(v.w);
    return r;
}

// ---------- rank-5 bank swizzle: slot(j) = j ^ ((j>>3)&0x1F) ----------
// (validated R7-R10: SQ_LDS_BANK_CONFLICT ~ 0; T1/T2 wave-local, T3 cross-wave)

__device__ __forceinline__ float fsig(float xv){ return __fdividef(1.f, 1.f + __expf(-xv)); }
__device__ __forceinline__ float ftanh(float xv){
    const float e = __expf(-2.f * xv);
    return __fdividef(1.f - e, 1.f + e);
}

// 3 layer-1 RY gates on the 3 thread-local bits (RZ phases folded out)
template<int WTOP>
__device__ __forceinline__ void rot3ry(v2f* s, const v2f* G){
    #pragma unroll
    for (int lb = 0; lb < 3; ++lb){
        const float cw = G[WTOP-lb].x, sw = G[WTOP-lb].y;
        #pragma unroll
        for (int k = 0; k < 8; ++k){
            if (k & (1 << lb)) continue;
            const int k1 = k | (1 << lb);
            const v2f a = s[k], b = s[k1];
            s[k]  = a*cw - b*sw;
            s[k1] = a*sw + b*cw;
        }
    }
}

extern "C" __global__ void __launch_bounds__(NT)
qlstm_kernel(const float* __restrict__ x,  const float* __restrict__ h0,
             const float* __restrict__ c0, const float* __restrict__ qw,
             const float* __restrict__ Wf, const float* __restrict__ bfp,
             const float* __restrict__ Wi, const float* __restrict__ bip,
             const float* __restrict__ Wc, const float* __restrict__ bcp,
             const float* __restrict__ Wo, const float* __restrict__ bop,
             float* __restrict__ out)
{
    __shared__ v2f S[NS];                  // single state buffer (rank-5 swizzled)
    __shared__ v2f matp[NQ][4];            // layer-0 Rot matrices (full, for vv build)
    __shared__ v2f vvx[8][2];              // x-wire product-state vectors (this step)
    __shared__ float xs[TT*8];             // preloaded x for this batch element
    __shared__ float4 red4[8];             // per-wave partial expectations
    __shared__ float4 qh[TT];              // q history for epilogue LSTM scan

    const int b    = blockIdx.x;
    const int tid  = threadIdx.x;
    const int wave = tid >> 6;
    const int lane = tid & 63;

    // ---- one-time init: layer-0 matrices ----
    if (tid < NQ){
        const int w = tid;
        const float phi = qw[w*3 + 0];
        const float th  = qw[w*3 + 1];
        const float om  = qw[w*3 + 2];
        float cth, sth, cap, sap, cam, sam;
        sincosf(0.5f*th, &sth, &cth);
        sincosf(0.5f*(phi+om), &sap, &cap);
        sincosf(0.5f*(phi-om), &sam, &cam);
        v2f m00; m00.x =  cap*cth; m00.y = -sap*cth;
        v2f m01; m01.x = -cam*sth; m01.y = -sam*sth;
        v2f m10; m10.x =  cam*sth; m10.y = -sam*sth;
        v2f m11; m11.x =  cap*cth; m11.y =  sap*cth;
        matp[w][0] = m00; matp[w][1] = m01;
        matp[w][2] = m10; matp[w][3] = m11;
    }
    if (tid >= 256) xs[tid - 256] = x[b*(TT*8) + (tid - 256)];

    // ---- layer-1 per-thread constants: RY (c,s), Dphi folds ----
    // wire w <-> j bit 11-w; j = (tid<<3)|k: wires 0..8 -> tid bits 8..0; wires 9,10,11 -> k bits 2,1,0
    v2f G[NQ];
    #pragma unroll
    for (int w = 0; w < NQ; ++w){
        float cg, sg; sincosf(0.5f*qw[(NQ + w)*3 + 1], &sg, &cg);
        G[w].x = cg; G[w].y = sg;
    }
    v2f Zphi;
    {
        float A = 0.f;
        #pragma unroll
        for (int w = 0; w <= 8; ++w){
            const float ph = qw[(NQ + w)*3 + 0];
            A += ((tid >> (8 - w)) & 1) ? ph : -ph;
        }
        float sa, ca; sincosf(0.5f*A, &sa, &ca);
        Zphi.x = ca; Zphi.y = sa;
    }
    v2f dd[8];
    {
        const float p9  = qw[(NQ + 9)*3 + 0];
        const float p10 = qw[(NQ +10)*3 + 0];
        const float p11 = qw[(NQ +11)*3 + 0];
        #pragma unroll
        for (int k = 0; k < 8; ++k){
            const float Bq = 0.5f*(((k&4)? p9 : -p9) + ((k&2)? p10 : -p10) + ((k&1)? p11 : -p11));
            float sb, cb; sincosf(Bq, &sb, &cb);
            dd[k].x = cb; dd[k].y = sb;
        }
    }

    // chain constants for wire cw = tid&3 (h-wires 8+cw), every lane
    const int cw = tid & 3;
    const float WfC=Wf[cw], bfC=bfp[cw], WiC=Wi[cw], biC=bip[cw];
    const float WcC=Wc[cw], bcC=bcp[cw], WoC=Wo[cw], boC=bop[cw];
    float c4 = c0[b*HH + cw];
    const float h_init = h0[b*HH + cw];
    __syncthreads();

    // hoist chain matrices (layer-0, wire 8+cw)
    const v2f M8w0 = matp[8+cw][0], M8w1 = matp[8+cw][1];
    const v2f M8w2 = matp[8+cw][2], M8w3 = matp[8+cw][3];

    // t=0 x-wire vvx by threads 128..135
    if (tid >= 128 && tid < 136){
        const int w = tid - 128;
        float sa, ca; sincosf(0.5f*xs[w], &sa, &ca);
        const v2f M00=matp[w][0], M01=matp[w][1], M10=matp[w][2], M11=matp[w][3];
        v2f t0v; t0v.x = M00.x*ca + M01.y*sa; t0v.y = M00.y*ca - M01.x*sa;
        v2f t1v; t1v.x = M10.x*ca + M11.y*sa; t1v.y = M10.y*ca - M11.x*sa;
        vvx[w][0] = t0v; vvx[w][1] = t1v;
    }
    // t=0 h-wire vectors: each lane computes its own wire's vector, DPP quad-broadcast
    // (quad lane j has cw==j, so qperm:[j,j,j,j] == old vvh[wave][j])
    v4f hv0, hv1, hv2, hv3;
    {
        float sa, ca; sincosf(0.5f*h_init, &sa, &ca);
        v4f hw;
        hw.x = M8w0.x*ca + M8w1.y*sa;  hw.y = M8w0.y*ca - M8w1.x*sa;
        hw.z = M8w2.x*ca + M8w3.y*sa;  hw.w = M8w2.y*ca - M8w3.x*sa;
        hv0 = qperm4<0x00>(hw); hv1 = qperm4<0x55>(hw);
        hv2 = qperm4<0xAA>(hw); hv3 = qperm4<0xFF>(hw);
    }
    __syncthreads();

    // ---- per-thread constants ----
    const float sg0 = (__builtin_parity(tid & (gM0 & 0x1FFu)) ? -1.f : 1.f);
    const float sg1 = (__builtin_parity(tid & (gM1 & 0x1FFu)) ? -1.f : 1.f);
    const float sg2 = (__builtin_parity(tid & (gM2 & 0x1FFu)) ? -1.f : 1.f);
    const float sg3 = (__builtin_parity(tid & (gM3 & 0x1FFu)) ? -1.f : 1.f);
    const int bA = (tid << 3) ^ (tid & 31);                                  // cfg A: ^ k
    const int bB = (tid & 7) ^ (((tid >> 3) & 3) << 3) ^ ((tid >> 3) << 6);  // cfg B: ^ 9k
    const int bC = ((tid & 63) ^ ((tid >> 3) & 7)) | ((tid >> 6) << 9);      // cfg C: ^ (k<<6 | (k&3)<<3)
    const int bD = tid ^ ((tid >> 3) & 31);                                  // cfg D: + (k<<9)
    const int s2 = ((tid>>6) ^ (tid>>7)) & 1;
    const int s3 = ((tid>>5) ^ (tid>>6)) & 1;
    const int s4 = ((tid>>4) ^ (tid>>5)) & 1;
    const int s5 = ((tid>>3) ^ (tid>>4)) & 1;
    const int s6 = ((tid>>2) ^ (tid>>3)) & 1;
    const int s7 = ((tid>>1) ^ (tid>>2)) & 1;
    const int s8 = ( tid     ^ (tid>>1)) & 1;
    const int t8  = (tid >> 8) & 1;
    const int t78 = ((tid>>7) ^ (tid>>8)) & 1;
    const int t0  = tid & 1;
    const v2f* vf = &vvx[0][0];

    // ---- carried x-only product parts (software pipeline across the backedge) ----
    v2f QxZ, Ux0, Ux1;
    {
        const v2f e2 = vf[ 4+s2], e3 = vf[ 6+s3], e4 = vf[ 8+s4];
        const v2f e5 = vf[10+s5], e6 = vf[12+s6], e7 = vf[14+s7];
        QxZ = pk_cmul(pk_cmul(pk_cmul(e2,e3), pk_cmul(e4,e5)),
                      pk_cmul(pk_cmul(e6,e7), Zphi));
        const v2f v0a = vf[0], v0b = vf[1], v1a = vf[2], v1b = vf[3];
        const v2f ua0 = t8 ? v0b : v0a,  ua1 = t8 ? v0a : v0b;
        const v2f ub0 = t78 ? v1b : v1a, ub1 = t78 ? v1a : v1b;
        Ux0 = pk_cmul(ua0, ub0); Ux1 = pk_cmul(ua1, ub1);
    }

    v2f amp[8];

    #pragma unroll 1
    for (int t = 0; t < TT; ++t){
        // ---- finish product build with h-dependent parts ----
        v2f e8; e8.x = s8 ? hv0.z : hv0.x;  e8.y = s8 ? hv0.w : hv0.y;
        const v2f Q   = pk_cmul(QxZ, e8);
        const v2f QU0 = pk_cmul(Q, Ux0);
        const v2f QU1 = pk_cmul(Q, Ux1);
        v2f v9a; v9a.x = hv1.x; v9a.y = hv1.y;
        v2f v9b; v9b.x = hv1.z; v9b.y = hv1.w;
        const v2f v9s0 = t0 ? v9b : v9a, v9s1 = t0 ? v9a : v9b;
        v2f v10a; v10a.x = hv2.x; v10a.y = hv2.y;
        v2f v10b; v10b.x = hv2.z; v10b.y = hv2.w;
        v2f v11a; v11a.x = hv3.x; v11a.y = hv3.y;
        v2f v11b; v11b.x = hv3.z; v11b.y = hv3.w;
        const v2f P2_0 = pk_cmul(v10a, v11a), P2_1 = pk_cmul(v10a, v11b);
        const v2f P2_2 = pk_cmul(v10b, v11a), P2_3 = pk_cmul(v10b, v11b);
        #pragma unroll
        for (int k = 0; k < 8; ++k){
            const int g = k ^ (k >> 1);
            const v2f base = (k & 1) ? QU1 : QU0;
            const v2f w9   = (g & 4) ? v9s1 : v9s0;
            const v2f p2   = (g&3)==0 ? P2_0 : (g&3)==1 ? P2_1 : (g&3)==2 ? P2_2 : P2_3;
            amp[k] = pk_cmul(pk_cmul(base, w9), pk_cmul(p2, dd[k]));
        }

        // ---- 12 layer-1 RY gates in 4 rounds; T1/T2 wave-local (fence only) ----
        rot3ry<11>(amp, G);                      // wires 11,10,9 (j bits 0..2)
        #pragma unroll
        for (int k = 0; k < 8; ++k) S[bA ^ k] = amp[k];                 // T1 write (cfg A)
        asm volatile("" ::: "memory");
        #pragma unroll
        for (int k = 0; k < 8; ++k) amp[k] = S[bB ^ (9*k)];             // T1 read (cfg B)
        rot3ry<8>(amp, G);                       // wires 8,7,6 (j bits 3..5)
        #pragma unroll
        for (int k = 0; k < 8; ++k) S[bB ^ (9*k)] = amp[k];             // T2 write (in place)
        asm volatile("" ::: "memory");
        #pragma unroll
        for (int k = 0; k < 8; ++k) amp[k] = S[bC ^ ((k<<6) | ((k&3)<<3))]; // T2 read (cfg C)
        rot3ry<5>(amp, G);                       // wires 5,4,3 (j bits 6..8)
        #pragma unroll
        for (int k = 0; k < 8; ++k) S[bC ^ ((k<<6) | ((k&3)<<3))] = amp[k]; // T3 write (in place)
        __syncthreads();                         // barrier 1 (cross-wave transpose)
        #pragma unroll
        for (int k = 0; k < 8; ++k) amp[k] = S[bD + (k<<9)];            // T3 read (cfg D)
        rot3ry<2>(amp, G);                       // wires 2,1,0 (j bits 9..11)

        // ---- CNOT layer 1 folded into <Z_g>; j = (k<<9)|tid ----
        v2f a01; a01.x = 0.f; a01.y = 0.f;
        v2f a23; a23.x = 0.f; a23.y = 0.f;
        expk<0>(amp, a01, a23);
        float p0 = a01.x * sg0, p1 = a01.y * sg1;
        float p2s = a23.x * sg2, p3 = a23.y * sg3;
        p0 = wsum(p0); p1 = wsum(p1); p2s = wsum(p2s); p3 = wsum(p3);   // lane 63 has sums
        if (lane == 63) red4[wave] = make_float4(p0, p1, p2s, p3);
        // next step's x-wire vvx (consumed pre-T3-barrier; new values read post-barrier2)
        if (tid >= 128 && tid < 136){
            const int w  = tid - 128;
            const int tn = (t + 1 < TT) ? t + 1 : t;
            float sa, ca; __sincosf(0.5f*xs[tn*8 + w], &sa, &ca);
            const v2f M00=matp[w][0], M01=matp[w][1], M10=matp[w][2], M11=matp[w][3];
            v2f t0v; t0v.x = M00.x*ca + M01.y*sa; t0v.y = M00.y*ca - M01.x*sa;
            v2f t1v; t1v.x = M10.x*ca + M11.y*sa; t1v.y = M10.y*ca - M11.x*sa;
            vvx[w][0] = t0v; vvx[w][1] = t1v;
        }
        __syncthreads();                         // barrier 2 (red4 + vvx visibility)

        // ---- q-sum (LDS reads first so they overlap with the x-part below) ----
        float q0=0.f, q1=0.f, q2=0.f, q3=0.f;
        #pragma unroll
        for (int i = 0; i < 8; ++i){
            const float4 r = red4[i];
            q0 += r.x; q1 += r.y; q2 += r.z; q3 += r.w;
        }

        // ---- x-only product parts for t+1 (independent of q; fills exp-chain bubbles) ----
        {
            const v2f e2 = vf[ 4+s2], e3 = vf[ 6+s3], e4 = vf[ 8+s4];
            const v2f e5 = vf[10+s5], e6 = vf[12+s6], e7 = vf[14+s7];
            QxZ = pk_cmul(pk_cmul(pk_cmul(e2,e3), pk_cmul(e4,e5)),
                          pk_cmul(pk_cmul(e6,e7), Zphi));
            const v2f v0a = vf[0], v0b = vf[1], v1a = vf[2], v1b = vf[3];
            const v2f ua0 = t8 ? v0b : v0a,  ua1 = t8 ? v0a : v0b;
            const v2f ub0 = t78 ? v1b : v1a, ub1 = t78 ? v1a : v1b;
            Ux0 = pk_cmul(ua0, ub0); Ux1 = pk_cmul(ua1, ub1);
        }

        if (tid == 0) qh[t] = make_float4(q0, q1, q2, q3);   // history for epilogue

        // ---- tail: every lane computes its wire's chain; DPP quad-broadcast (no LDS) ----
        {
            const float fg = fsig (q0*WfC + bfC);
            const float ig = fsig (q1*WiC + biC);
            const float cg = ftanh(q2*WcC + bcC);
            const float og = fsig (q3*WoC + boC);
            c4 = fg*c4 + ig*cg;
            const float hj = og * ftanh(c4);
            float sa, ca; __sincosf(0.5f*hj, &sa, &ca);
            v4f hw;
            hw.x = M8w0.x*ca + M8w1.y*sa;  hw.y = M8w0.y*ca - M8w1.x*sa;
            hw.z = M8w2.x*ca + M8w3.y*sa;  hw.w = M8w2.y*ca - M8w3.x*sa;
            hv0 = qperm4<0x00>(hw); hv1 = qperm4<0x55>(hw);
            hv2 = qperm4<0xAA>(hw); hv3 = qperm4<0xFF>(hw);
        }
    }

    // ---- epilogue: per-channel LSTM scan over the q history (parallel over H) ----
    __syncthreads();
    if (tid < HH){
        const float wfE=Wf[tid], bfE=bfp[tid], wiE=Wi[tid], biE=bip[tid];
        const float wcE=Wc[tid], bcE=bcp[tid], woE=Wo[tid], boE=bop[tid];
        float cc = c0[b*HH + tid];
        float hh = 0.f;
        #pragma unroll 1
        for (int t = 0; t < TT; ++t){
            const float4 q = qh[t];
            const float fg = fsig (q.x*wfE + bfE);
            const float ig = fsig (q.y*wiE + biE);
            const float cg = ftanh(q.z*wcE + bcE);
            const float og = fsig (q.w*woE + boE);
            cc = fg*cc + ig*cg;
            hh = og * ftanh(cc);
        }
        out[b*HH + tid]         = hh;
        out[BB*HH + b*HH + tid] = cc;
    }
}

extern "C" void kernel_launch(void* const* d_in, const int* in_sizes, int n_in,
                              void* d_out, int out_size, void* d_ws, size_t ws_size,
                              hipStream_t stream)
{
    (void)in_sizes; (void)n_in; (void)d_ws; (void)ws_size; (void)out_size;
    const float* x  = (const float*)d_in[0];
    const float* h0 = (const float*)d_in[1];
    const float* c0 = (const float*)d_in[2];
    const float* qw = (const float*)d_in[3];
    const float* Wf = (const float*)d_in[4];
    const float* bf = (const float*)d_in[5];
    const float* Wi = (const float*)d_in[6];
    const float* bi = (const float*)d_in[7];
    const float* Wc = (const float*)d_in[8];
    const float* bc = (const float*)d_in[9];
    const float* Wo = (const float*)d_in[10];
    const float* bo = (const float*)d_in[11];
    qlstm_kernel<<<BB, NT, 0, stream>>>(x, h0, c0, qw, Wf, bf, Wi, bi,
                                        Wc, bc, Wo, bo, (float*)d_out);
}